// Round 1
// 175.197 us; speedup vs baseline: 1.0282x; 1.0282x over previous
//
#include <hip/hip_runtime.h>

// ---------------------------------------------------------------------------
// FlashAttention block: out = proj(causal_attn(qkv(x)))
// B=2, T=2048, D=1024, H=16, dhead=64.  All GEMMs + attention in bf16 MFMA
// (16x16x32), fp32 accumulate.  fp32 output.
// R20 = R17 + in-register softmax for attention:
//   - QK^T computed swapped (S^T = mfma(K,Q); same registers, same loads) so
//     each lane holds P in C-layout (key-major).  exp2 -> v_cvt_pk_bf16_f32
//     -> permlane32_swap+permlane16_swap transpose rebuilds the PV A-frags
//     entirely in registers.  Ps LDS buffer and its 16 ds_write_b16 +
//     lgkmcnt(0) + 2 ds_read_b128 round-trip are GONE from the per-tile
//     critical chain.
//   - attn LDS 40KB -> 32KB: 4 blocks/CU now fit with margin under the
//     runtime LDS reserve (R18 evidence: 4x40960 = exactly 160KB -> 4th
//     block never materialized).
//   - s_setprio(1) around QK and PV MFMA clusters (T5; attn-proven).
// GEMMs/prep unchanged from R17: gemm 128x128 / 128x64 with 3-deep LDS
// pipeline, vmcnt(loads-per-tile) waits, raw s_barrier, XOR-swizzled staging;
// attn: persistent 1024-block schedule, XCD-pinned heads, fixed-m=0 softmax,
// MFMA ones-trick row sums.
// ---------------------------------------------------------------------------

#define B_   2
#define T_   2048
#define D_   1024
#define H_   16
#define DH_  64
#define M_   (B_ * T_)       // 4096
#define N1_  (3 * D_)        // 3072
// qscale folds 1/sqrt(dhead) and log2(e) so softmax uses native exp2
#define QSCALE (0.125f * 1.44269504088896340736f)

typedef __bf16 bf16x8 __attribute__((ext_vector_type(8)));
typedef __bf16 bf16x4 __attribute__((ext_vector_type(4)));
typedef float  f32x4  __attribute__((ext_vector_type(4)));
typedef int    i32x2  __attribute__((ext_vector_type(2)));
typedef unsigned u32x4 __attribute__((ext_vector_type(4)));

#define MFMA16(a, b, c) __builtin_amdgcn_mfma_f32_16x16x32_bf16((a), (b), (c), 0, 0, 0)

// async global->LDS, 16B per lane; LDS dest = base + lane*16 (wave-uniform base)
#define GLOAD16(gp, lp)                                                        \
    __builtin_amdgcn_global_load_lds(                                          \
        (const __attribute__((address_space(1))) void*)(gp),                   \
        (__attribute__((address_space(3))) void*)(lp), 16, 0, 0)

#define DRAIN_ALL() __asm__ volatile("s_waitcnt vmcnt(0) lgkmcnt(0)" ::: "memory")

#if defined(__has_builtin)
#if __has_builtin(__builtin_amdgcn_permlane32_swap) && \
    __has_builtin(__builtin_amdgcn_permlane16_swap)
#define HAVE_PERMLANE_SWAP 1
#endif
#endif

// Transpose step for the in-register P-fragment rebuild.
// Input: a = W_g replicated on all qd groups, b = W_{g+1} likewise
//   (per-16-lane groups: a=[A(qd0),A(qd1),A(qd2),A(qd3)], b analogous).
// Output: a = [Ag(qd0), Ag(qd2), Ag1(qd0), Ag1(qd2)]   (even source qd)
//         b = [Ag(qd1), Ag(qd3), Ag1(qd1), Ag1(qd3)]   (odd  source qd)
// via v_permlane32_swap (vdst upper 32 lanes <-> src lower 32) followed by
// v_permlane16_swap (vdst odd 16-rows <-> src even 16-rows).
__device__ __forceinline__ void xpose_pair(unsigned& a, unsigned& b) {
#if defined(HAVE_PERMLANE_SWAP)
    i32x2 r1 = __builtin_amdgcn_permlane32_swap((int)a, (int)b, false, false);
    i32x2 r2 = __builtin_amdgcn_permlane16_swap(r1[0], r1[1], false, false);
    a = (unsigned)r2[0];
    b = (unsigned)r2[1];
#else
    // fallback: explicit gather via shfl (2 shfl + 1 select per word)
    const int lane = threadIdx.x & 63;
    const int lo   = lane & 15;
    const int srcE = lo + 32 * ((lane >> 4) & 1);
    const int srcO = srcE + 16;
    int aE = __shfl((int)a, srcE, 64), bE = __shfl((int)b, srcE, 64);
    int aO = __shfl((int)a, srcO, 64), bO = __shfl((int)b, srcO, 64);
    unsigned w0 = (lane & 32) ? (unsigned)bE : (unsigned)aE;
    unsigned w2 = (lane & 32) ? (unsigned)bO : (unsigned)aO;
    a = w0;
    b = w2;
#endif
}

// ------------------------------ fused prep ---------------------------------
// One launch: blocks [0,4096) convert x fp32->bf16 (4 elems/thread);
// blocks [4096,7168) transpose w_attn [1024][3072] -> bf16 [3072][1024];
// blocks [7168,8192) transpose w_proj [1024][1024] -> bf16 [1024][1024].

__global__ __launch_bounds__(256) void prep_kernel(
    const float* __restrict__ x,      __bf16* __restrict__ xb,
    const float* __restrict__ w_attn, __bf16* __restrict__ wattnT,
    const float* __restrict__ w_proj, __bf16* __restrict__ wprojT) {
    __shared__ float tile[32][33];
    int id = blockIdx.x;
    if (id < 4096) {                       // x convert
        int i = (id * 256 + threadIdx.x) * 4;
        float4 f = *(const float4*)(x + i);
        bf16x4 o;
        o[0] = (__bf16)f.x; o[1] = (__bf16)f.y; o[2] = (__bf16)f.z; o[3] = (__bf16)f.w;
        *(bf16x4*)(xb + i) = o;
        return;
    }
    id -= 4096;
    const float* in;
    __bf16* out;
    int C, bx, by;
    if (id < 3072) { in = w_attn; out = wattnT; C = N1_; bx = id % 96; by = id / 96; }
    else { id -= 3072; in = w_proj; out = wprojT; C = D_; bx = id & 31; by = id >> 5; }
    const int tx = threadIdx.x & 31;
    const int ty = threadIdx.x >> 5;       // 0..7
    const int c0 = bx * 32;
    const int r0 = by * 32;
#pragma unroll
    for (int i = 0; i < 4; i++)
        tile[ty + i * 8][tx] = in[(size_t)(r0 + ty + i * 8) * C + c0 + tx];
    __syncthreads();
#pragma unroll
    for (int i = 0; i < 4; i++)
        out[(size_t)(c0 + ty + i * 8) * D_ + r0 + tx] = (__bf16)tile[tx][ty + i * 8];
}

// ------------------------------- MFMA GEMM ---------------------------------
// C[M][N] = A[M][K] @ Bt[N][K]^T + bias.  TM x TN tile, 256 threads (4
// waves), wave covers (TM/2) x (TN/2) as (TM/32)x(TN/32) frags of 16x16,
// BK=32.  Pipeline: 3 LDS buffers, 2-deep global_load_lds prefetch,
// s_waitcnt vmcnt(loads-per-tile) (0 only on last iter), raw s_barrier.
// LDS rows are 32 elems (64 B); K-chunk slot s of row r holds global chunk
// s ^ ((r>>1)&3) so frag ds_read_b128 spreads all 8 bank groups (R16).
// EPI 0: scatter to Q (scaled), K (direct); V via LDS transpose tile for
// coalesced Vt stores.  EPI 1: fp32 out + bias.

template <int EPI, int TM, int TN>
__global__ __launch_bounds__(256) void gemm_bt_kernel(
    const __bf16* __restrict__ A, const __bf16* __restrict__ Bt,
    const float* __restrict__ bias, float* __restrict__ Cout,
    __bf16* __restrict__ Q, __bf16* __restrict__ Kb, __bf16* __restrict__ Vt,
    int M, int N, int K) {
    constexpr int MI  = TM / 32;          // m-frags per wave
    constexpr int NJ  = TN / 32;          // n-frags per wave
    constexpr int WM  = MI * 16;          // rows per wave
    constexpr int WN  = NJ * 16;          // cols per wave
    constexpr int ACH = TM / 64;          // A-chunk rounds per thread
    constexpr int BCH = TN / 64;          // B-chunk rounds per thread
    constexpr int RP  = TM + 8;           // vt tile row stride (elems)
    constexpr int SMEM_STAGE = 3 * (TM + TN) * 32 * 2;
    constexpr int SMEM_VT    = (EPI == 0) ? TN * RP * 2 : 0;
    constexpr int SMEM_BYTES = SMEM_STAGE > SMEM_VT ? SMEM_STAGE : SMEM_VT;
    __shared__ __align__(16) char smem[SMEM_BYTES];
    __bf16* AsB = (__bf16*)smem;          // [3][TM*32]
    __bf16* BsB = AsB + 3 * TM * 32;      // [3][TN*32]

    const int tid  = threadIdx.x;
    const int lane = tid & 63;
    const int wave = tid >> 6;
    const int lo   = lane & 15;
    const int qd   = lane >> 4;
    const int wm   = (wave >> 1) * WM;
    const int wn   = (wave & 1) * WN;
    const int m0   = blockIdx.y * TM;
    const int n0   = blockIdx.x * TN;

    // staging decode: chunk g -> LDS byte g*16; row = g>>2, slot = g&3,
    // global k-chunk = slot ^ ((row>>1)&3) = (g&3) ^ ((g>>3)&3)
    const __bf16* gA[ACH];
    const __bf16* gB[BCH];
#pragma unroll
    for (int c = 0; c < ACH; c++) {
        int g = tid + 256 * c;
        int cc = (g & 3) ^ ((g >> 3) & 3);
        gA[c] = A + (size_t)(m0 + (g >> 2)) * K + cc * 8;
    }
#pragma unroll
    for (int c = 0; c < BCH; c++) {
        int g = tid + 256 * c;
        int cc = (g & 3) ^ ((g >> 3) & 3);
        gB[c] = Bt + (size_t)(n0 + (g >> 2)) * K + cc * 8;
    }

    f32x4 acc[MI][NJ] = {};
    const int nk = K >> 5;               // >= 32 here

    // prologue: stage tiles 0 and 1 (2-deep)
#pragma unroll
    for (int pb = 0; pb < 2; pb++) {
        const int k0 = pb << 5;
#pragma unroll
        for (int c = 0; c < ACH; c++)
            GLOAD16(gA[c] + k0, AsB + pb * TM * 32 + (tid + 256 * c) * 8);
#pragma unroll
        for (int c = 0; c < BCH; c++)
            GLOAD16(gB[c] + k0, BsB + pb * TN * 32 + (tid + 256 * c) * 8);
    }

    for (int kt = 0; kt < nk; kt++) {
        const int cur = kt % 3;
        // tile kt landed; keep tile kt+1's (ACH+BCH) loads in flight
        if (kt + 1 < nk) {
            __asm__ volatile("s_waitcnt vmcnt(%0) lgkmcnt(0)" ::
                             "i"(ACH + BCH) : "memory");
        } else {
            __asm__ volatile("s_waitcnt vmcnt(0) lgkmcnt(0)" ::: "memory");
        }
        __asm__ volatile("s_barrier" ::: "memory");
        if (kt + 2 < nk) {               // prefetch tile kt+2 (buf == kt-1's)
            const int k0n = (kt + 2) << 5;
            const int nb  = (kt + 2) % 3;
#pragma unroll
            for (int c = 0; c < ACH; c++)
                GLOAD16(gA[c] + k0n, AsB + nb * TM * 32 + (tid + 256 * c) * 8);
#pragma unroll
            for (int c = 0; c < BCH; c++)
                GLOAD16(gB[c] + k0n, BsB + nb * TN * 32 + (tid + 256 * c) * 8);
        }
        bf16x8 af[MI], bfr[NJ];
#pragma unroll
        for (int i = 0; i < MI; i++) {
            const int row = wm + i * 16 + lo;
            af[i] = *(const bf16x8*)(AsB + cur * TM * 32 + row * 32 +
                                     ((qd ^ ((row >> 1) & 3)) << 3));
        }
#pragma unroll
        for (int j = 0; j < NJ; j++) {
            const int row = wn + j * 16 + lo;
            bfr[j] = *(const bf16x8*)(BsB + cur * TN * 32 + row * 32 +
                                      ((qd ^ ((row >> 1) & 3)) << 3));
        }
#pragma unroll
        for (int i = 0; i < MI; i++)
#pragma unroll
            for (int j = 0; j < NJ; j++)
                acc[i][j] = MFMA16(af[i], bfr[j], acc[i][j]);
    }

    if (EPI == 0 && n0 >= 2 * D_) {
        // ---- V region: LDS transpose tile -> coalesced Vt stores ----
        __bf16* vt = (__bf16*)smem;       // [TN gn-local][RP t-local]
        __syncthreads();                  // all staging reads done
#pragma unroll
        for (int i = 0; i < MI; i++)
#pragma unroll
            for (int j = 0; j < NJ; j++)
#pragma unroll
                for (int r = 0; r < 4; r++) {
                    const int lrow = wn + j * 16 + lo;         // gn-local
                    const int lcol = wm + i * 16 + qd * 4 + r; // t-local
                    vt[lrow * RP + lcol] =
                        (__bf16)(acc[i][j][r] + bias[n0 + lrow]);
                }
        __syncthreads();
        constexpr int TPR = 256 / TN;     // threads per gn-row
        constexpr int SEG = TM / TPR;     // elems per thread (contig)
        const int row = tid / TPR;        // 0..TN-1
        const int seg = tid % TPR;
        const int gn  = n0 + row;
        const int bhv = ((m0 >> 11) << 4) + ((gn >> 6) & 15);
        const int dd  = gn & 63;
        __bf16* dst = Vt + ((size_t)bhv * DH_ + dd) * T_ + (m0 & (T_ - 1)) + seg * SEG;
        const __bf16* src = vt + row * RP + seg * SEG;
#pragma unroll
        for (int kk = 0; kk < SEG / 8; kk++)   // 16B stores
            *(uint4*)(dst + kk * 8) = *(const uint4*)(src + kk * 8);
        return;
    }

#pragma unroll
    for (int i = 0; i < MI; i++) {
#pragma unroll
        for (int j = 0; j < NJ; j++) {
#pragma unroll
            for (int r = 0; r < 4; r++) {
                int gm = m0 + wm + i * 16 + qd * 4 + r;   // C/D row
                int gn = n0 + wn + j * 16 + lo;           // C/D col
                float v = acc[i][j][r] + bias[gn];
                if (EPI == 1) {
                    Cout[(size_t)gm * N + gn] = v;
                } else {
                    int which = gn >> 10;                 // 0=q 1=k (2 handled above)
                    int bh = ((gm >> 11) << 4) + ((gn >> 6) & 15);
                    int dd = gn & 63;
                    int t  = gm & (T_ - 1);
                    if (which == 0)
                        Q[((size_t)bh * T_ + t) * DH_ + dd] = (__bf16)(v * QSCALE);
                    else
                        Kb[((size_t)bh * T_ + t) * DH_ + dd] = (__bf16)v;
                }
            }
        }
    }
}

// ---------------------------- flash attention ------------------------------
// R20 kernel.  Grid 1024, 4 blocks/CU (32KB LDS -> fits under runtime
// reserve), balanced quadruple item map, heads XCD-pinned, K/V dbuf +
// prefetch, XOR-swizzled staging, fixed m=0 softmax (exact by shift
// invariance; masked -1e30 -> 0), MFMA ones-trick row sums.
// Softmax is fully in-register: S^T = mfma(K,Q) (identical register data as
// the unswapped form), exp2 in regs, v_cvt_pk_bf16_f32 packs r-pairs, and
// permlane32_swap+permlane16_swap rebuild the PV A-frags without LDS.

__global__ __launch_bounds__(256) void attn_kernel(
    const __bf16* __restrict__ Q,   // [BH][T][64], pre-scaled
    const __bf16* __restrict__ Kb,  // [BH][T][64]
    const __bf16* __restrict__ Vt,  // [BH][64][T]
    __bf16* __restrict__ O) {       // [B][T][H*64]
    __shared__ __bf16 Ks[2][64 * 64];     // [key][d]  2 x 8 KB, swizzled
    __shared__ __bf16 Vs[2][64 * 64];     // [d][key]  2 x 8 KB, swizzled

    const int tid  = threadIdx.x;
    const int wave = tid >> 6;
    const int lane = tid & 63;
    const int lo   = lane & 15;
    const int qd   = lane >> 4;

    // staging decode: chunk g -> LDS byte g*16; row=g>>3, cc_lds=g&7,
    // global cc = cc_lds ^ (row&7)
    const int g0  = wave * 128 + lane;
    const int g1  = g0 + 64;
    const int r0s = g0 >> 3, c0s = (g0 & 7) ^ (r0s & 7);
    const int r1s = g1 >> 3, c1s = (g1 & 7) ^ (r1s & 7);
    const int so0 = wave * 1024;
    const int so1 = wave * 1024 + 512;

    bf16x8 ones;
#pragma unroll
    for (int i = 0; i < 8; i++) ones[i] = (__bf16)1.0f;

    // balanced item map: 4 blocks a CU receives cost exactly 66 tiles
    const int k  = blockIdx.x;            // 0..1023
    const int j  = k >> 5;                // 0..31
    const int bh = k & 31;
    int x;
    if (j < 8)       x = 31 - j;
    else if (j < 16) x = j - 8;
    else if (j < 24) x = 39 - j;
    else             x = j - 16;

    const int b    = bh >> 4;
    const int h    = bh & 15;
    const int q0   = x * 64 + wave * 16;

    const __bf16* Qh = Q + (size_t)bh * T_ * DH_;
    const __bf16* Kh = Kb + (size_t)bh * T_ * DH_;
    const __bf16* Vh = Vt + (size_t)bh * DH_ * T_;

    // Q frags: lane holds Q[q0+lo][half*32 + qd*8 + j]
    // (used as the B operand of the swapped S^T mfma -- identical data)
    bf16x8 qa0 = *(const bf16x8*)(Qh + (size_t)(q0 + lo) * DH_ + qd * 8);
    bf16x8 qa1 = *(const bf16x8*)(Qh + (size_t)(q0 + lo) * DH_ + 32 + qd * 8);

    f32x4 oacc[4] = {};
    float lrow[4] = {0.0f, 0.0f, 0.0f, 0.0f};
    const int qrow  = q0 + qd * 4;
    const int ntile = x + 1;

    // prologue: stage tile 0 into buffer 0
    GLOAD16(Kh + (size_t)r0s * DH_ + c0s * 8, Ks[0] + so0);
    GLOAD16(Kh + (size_t)r1s * DH_ + c1s * 8, Ks[0] + so1);
    GLOAD16(Vh + (size_t)r0s * T_ + c0s * 8, Vs[0] + so0);
    GLOAD16(Vh + (size_t)r1s * T_ + c1s * 8, Vs[0] + so1);
    DRAIN_ALL();
    __syncthreads();

    for (int t = 0; t < ntile; t++) {
        const int j0  = t << 6;
        const int cur = t & 1;
        if (t + 1 < ntile) {             // prefetch next K/V tile
            const int j0n = j0 + 64;
            GLOAD16(Kh + (size_t)(j0n + r0s) * DH_ + c0s * 8, Ks[1 - cur] + so0);
            GLOAD16(Kh + (size_t)(j0n + r1s) * DH_ + c1s * 8, Ks[1 - cur] + so1);
            GLOAD16(Vh + (size_t)r0s * T_ + j0n + c0s * 8, Vs[1 - cur] + so0);
            GLOAD16(Vh + (size_t)r1s * T_ + j0n + c1s * 8, Vs[1 - cur] + so1);
        }

        // ---- S^T = K @ Q^T: lane (lo,qd) holds S[q=lo][key=16g+4qd+r] ----
        f32x4 s[4] = {};
        __builtin_amdgcn_s_setprio(1);
#pragma unroll
        for (int g = 0; g < 4; g++) {
            const int row = g * 16 + lo;
            const __bf16* kr = Ks[cur] + row * 64;
            bf16x8 kb0 = *(const bf16x8*)(kr + ((qd ^ (row & 7)) << 3));
            bf16x8 kb1 = *(const bf16x8*)(kr + (((4 + qd) ^ (row & 7)) << 3));
            s[g] = MFMA16(kb0, qa0, s[g]);
            s[g] = MFMA16(kb1, qa1, s[g]);
        }
        __builtin_amdgcn_s_setprio(0);

        // ---- causal mask (diagonal tile only; wave-uniform gate) ----
        if (j0 + 63 > q0) {
            const int qg = q0 + lo;
#pragma unroll
            for (int g = 0; g < 4; g++) {
                const int kbase = j0 + g * 16 + qd * 4;
#pragma unroll
                for (int r = 0; r < 4; r++)
                    s[g][r] = (kbase + r <= qg) ? s[g][r] : -1e30f;
            }
        }

        // ---- P = exp2(S) (fixed m=0), packed to bf16 pairs in-register ----
        // Aw[g] = pk(P[lo][16g+4qd+0], +1), Bw[g] = pk(+2, +3)
        unsigned Aw[4], Bw[4];
#pragma unroll
        for (int g = 0; g < 4; g++) {
            float p0 = __builtin_amdgcn_exp2f(s[g][0]);
            float p1 = __builtin_amdgcn_exp2f(s[g][1]);
            float p2 = __builtin_amdgcn_exp2f(s[g][2]);
            float p3 = __builtin_amdgcn_exp2f(s[g][3]);
            __asm__("v_cvt_pk_bf16_f32 %0, %1, %2" : "=v"(Aw[g]) : "v"(p0), "v"(p1));
            __asm__("v_cvt_pk_bf16_f32 %0, %1, %2" : "=v"(Bw[g]) : "v"(p2), "v"(p3));
        }
        // lane transpose: key-major C-layout -> q-row-major A-frags.
        // After xpose, lane (lo,Q): Aw[2g] = keys 8Q+{0,1} (+32g),
        // Bw[2g] = 8Q+{2,3}, Aw[2g+1] = 8Q+{4,5}, Bw[2g+1] = 8Q+{6,7}.
        xpose_pair(Aw[0], Aw[1]);
        xpose_pair(Bw[0], Bw[1]);
        xpose_pair(Aw[2], Aw[3]);
        xpose_pair(Bw[2], Bw[3]);
        u32x4 P0 = {Aw[0], Bw[0], Aw[1], Bw[1]};   // keys  0..31
        u32x4 P1 = {Aw[2], Bw[2], Aw[3], Bw[3]};   // keys 32..63
        bf16x8 pa0 = __builtin_bit_cast(bf16x8, P0);
        bf16x8 pa1 = __builtin_bit_cast(bf16x8, P1);

        // ---- row sums via MFMA ones-trick + O += P @ V ----
        f32x4 ps = {};
        __builtin_amdgcn_s_setprio(1);
        ps = MFMA16(pa0, ones, ps);
        ps = MFMA16(pa1, ones, ps);
#pragma unroll
        for (int c = 0; c < 4; c++) {
            const int row = c * 16 + lo;
            const __bf16* vr = Vs[cur] + row * 64;
            bf16x8 vb0 = *(const bf16x8*)(vr + ((qd ^ (row & 7)) << 3));
            bf16x8 vb1 = *(const bf16x8*)(vr + (((4 + qd) ^ (row & 7)) << 3));
            oacc[c] = MFMA16(pa0, vb0, oacc[c]);
            oacc[c] = MFMA16(pa1, vb1, oacc[c]);
        }
        __builtin_amdgcn_s_setprio(0);
#pragma unroll
        for (int r = 0; r < 4; r++) lrow[r] += ps[r];

        DRAIN_ALL();                 // prefetch landed + all LDS ops done
        __syncthreads();
    }

    // ---- normalize + store O as [B][T][H*64] bf16 ----
    float inv[4];
#pragma unroll
    for (int r = 0; r < 4; r++) inv[r] = 1.0f / lrow[r];
#pragma unroll
    for (int c = 0; c < 4; c++) {
#pragma unroll
        for (int r = 0; r < 4; r++) {
            float val = oacc[c][r] * inv[r];
            size_t idx = ((size_t)b * T_ + (qrow + r)) * D_ + h * DH_ + c * 16 + lo;
            O[idx] = (__bf16)val;
        }
    }
}

// -------------------------------- launcher ---------------------------------

extern "C" void kernel_launch(void* const* d_in, const int* in_sizes, int n_in,
                              void* d_out, int out_size, void* d_ws, size_t ws_size,
                              hipStream_t stream) {
    const float* x      = (const float*)d_in[0];
    const float* w_attn = (const float*)d_in[1];
    const float* b_attn = (const float*)d_in[2];
    const float* w_proj = (const float*)d_in[3];
    const float* b_proj = (const float*)d_in[4];
    float* out = (float*)d_out;

    const size_t MB = (size_t)1 << 20;
    if (ws_size < 48 * MB) return;   // need 48 MB scratch

    char* ws = (char*)d_ws;
    __bf16* xb     = (__bf16*)(ws);              //  8 MB  [M][D]
    __bf16* wattnT = (__bf16*)(ws + 8 * MB);     //  6 MB  [3D][D]
    __bf16* wprojT = (__bf16*)(ws + 14 * MB);    //  2 MB  [D][D]
    __bf16* Qb     = (__bf16*)(ws + 16 * MB);    //  8 MB  [BH][T][64]
    __bf16* Kb     = (__bf16*)(ws + 24 * MB);    //  8 MB  [BH][T][64]
    __bf16* Vt     = (__bf16*)(ws + 32 * MB);    //  8 MB  [BH][64][T]
    __bf16* Ob     = (__bf16*)(ws + 40 * MB);    //  8 MB  [M][D]

    // 1. fused prep: x convert + both weight transposes
    prep_kernel<<<dim3(8192), 256, 0, stream>>>(x, xb, w_attn, wattnT,
                                                w_proj, wprojT);
    // 2. QKV GEMM -> Q(scaled)/K/Vt  (128x128 tiles, pipelined, swizzled)
    gemm_bt_kernel<0, 128, 128><<<dim3(N1_ / 128, M_ / 128), 256, 0, stream>>>(
        xb, wattnT, b_attn, nullptr, Qb, Kb, Vt, M_, N1_, D_);
    // 3. causal flash attention (1024 blocks, 4/CU, in-register softmax)
    attn_kernel<<<dim3(1024), 256, 0, stream>>>(Qb, Kb, Vt, Ob);
    // 4. output projection (fp32 + bias), 128x64 tiles -> 512 blocks
    gemm_bt_kernel<1, 128, 64><<<dim3(D_ / 64, M_ / 128), 256, 0, stream>>>(
        Ob, wprojT, b_proj, out, nullptr, nullptr, nullptr, M_, D_, D_);
}

// Round 2
// 171.757 us; speedup vs baseline: 1.0488x; 1.0200x over previous
//
#include <hip/hip_runtime.h>

// ---------------------------------------------------------------------------
// FlashAttention block: out = proj(causal_attn(qkv(x)))
// B=2, T=2048, D=1024, H=16, dhead=64.  All GEMMs + attention in bf16 MFMA
// (16x16x32), fp32 accumulate.  fp32 output.
// R21 = R20 + QKV GEMM ported to the 256^2 deep-pipelined schedule
// (T2+T3+T4+T5, m201-style):
//   - BM=BN=256, BK=64 (2 K-slices of 32), 512 threads / 8 waves (2Mx4N),
//     acc 8x4 frags.  LDS 128KB: 2 tile-buffers x 2 ks-slices x (A+B),
//     4-slot XOR swizzle identical to the proven 128^2 staging.
//   - 4 load-stages per K-tile (Ak0,Bk0,Ak1,Bk1; 2 global_load_lds/thread
//     each), issued one per phase slot; drains are s_waitcnt vmcnt(6)
//     TWICE per tile (never 0 until the last tile) -> 3 stages always in
//     flight across barriers (T4, the m218 lever).
//   - 2 barriers per K-tile, each "lgkmcnt(0); s_barrier" (DS reads fully
//     drained at the barrier -> slot-overwrite race closed; every slot
//     rewrite is >=1 barrier after its last reader).
//   - s_setprio(1) around each 16-MFMA cluster (T5).
//   - grid 12x16 = 192 blocks (1/CU), bijective XCD swizzle (192 % 8 == 0).
//   - epilogues (Q scaled / K scatter, V LDS-transpose -> coalesced Vt)
//     reuse the proven formulas; vt tile [256][264] bf16 = 132KB.
// attn: R20 kernel (in-register softmax via swapped QK^T + cvt_pk +
// permlane swaps, 32KB LDS, setprio).  proj GEMM + prep unchanged.
// ---------------------------------------------------------------------------

#define B_   2
#define T_   2048
#define D_   1024
#define H_   16
#define DH_  64
#define M_   (B_ * T_)       // 4096
#define N1_  (3 * D_)        // 3072
// qscale folds 1/sqrt(dhead) and log2(e) so softmax uses native exp2
#define QSCALE (0.125f * 1.44269504088896340736f)

typedef __bf16 bf16x8 __attribute__((ext_vector_type(8)));
typedef __bf16 bf16x4 __attribute__((ext_vector_type(4)));
typedef float  f32x4  __attribute__((ext_vector_type(4)));
typedef int    i32x2  __attribute__((ext_vector_type(2)));
typedef unsigned u32x4 __attribute__((ext_vector_type(4)));

#define MFMA16(a, b, c) __builtin_amdgcn_mfma_f32_16x16x32_bf16((a), (b), (c), 0, 0, 0)

// async global->LDS, 16B per lane; LDS dest = base + lane*16 (wave-uniform base)
#define GLOAD16(gp, lp)                                                        \
    __builtin_amdgcn_global_load_lds(                                          \
        (const __attribute__((address_space(1))) void*)(gp),                   \
        (__attribute__((address_space(3))) void*)(lp), 16, 0, 0)

#define DRAIN_ALL() __asm__ volatile("s_waitcnt vmcnt(0) lgkmcnt(0)" ::: "memory")

// drain own VMEM to N, drain all DS, then barrier (single asm so the drain
// provably precedes the barrier regardless of scheduling)
#define WAIT_BAR(N)                                                            \
    __asm__ volatile("s_waitcnt vmcnt(" #N ") lgkmcnt(0)\n\ts_barrier" ::: "memory")

#if defined(__has_builtin)
#if __has_builtin(__builtin_amdgcn_permlane32_swap) && \
    __has_builtin(__builtin_amdgcn_permlane16_swap)
#define HAVE_PERMLANE_SWAP 1
#endif
#endif

// Transpose step for the in-register P-fragment rebuild (see attn_kernel).
__device__ __forceinline__ void xpose_pair(unsigned& a, unsigned& b) {
#if defined(HAVE_PERMLANE_SWAP)
    i32x2 r1 = __builtin_amdgcn_permlane32_swap((int)a, (int)b, false, false);
    i32x2 r2 = __builtin_amdgcn_permlane16_swap(r1[0], r1[1], false, false);
    a = (unsigned)r2[0];
    b = (unsigned)r2[1];
#else
    const int lane = threadIdx.x & 63;
    const int lo   = lane & 15;
    const int srcE = lo + 32 * ((lane >> 4) & 1);
    const int srcO = srcE + 16;
    int aE = __shfl((int)a, srcE, 64), bE = __shfl((int)b, srcE, 64);
    int aO = __shfl((int)a, srcO, 64), bO = __shfl((int)b, srcO, 64);
    unsigned w0 = (lane & 32) ? (unsigned)bE : (unsigned)aE;
    unsigned w2 = (lane & 32) ? (unsigned)bO : (unsigned)aO;
    a = w0;
    b = w2;
#endif
}

// ------------------------------ fused prep ---------------------------------

__global__ __launch_bounds__(256) void prep_kernel(
    const float* __restrict__ x,      __bf16* __restrict__ xb,
    const float* __restrict__ w_attn, __bf16* __restrict__ wattnT,
    const float* __restrict__ w_proj, __bf16* __restrict__ wprojT) {
    __shared__ float tile[32][33];
    int id = blockIdx.x;
    if (id < 4096) {                       // x convert
        int i = (id * 256 + threadIdx.x) * 4;
        float4 f = *(const float4*)(x + i);
        bf16x4 o;
        o[0] = (__bf16)f.x; o[1] = (__bf16)f.y; o[2] = (__bf16)f.z; o[3] = (__bf16)f.w;
        *(bf16x4*)(xb + i) = o;
        return;
    }
    id -= 4096;
    const float* in;
    __bf16* out;
    int C, bx, by;
    if (id < 3072) { in = w_attn; out = wattnT; C = N1_; bx = id % 96; by = id / 96; }
    else { id -= 3072; in = w_proj; out = wprojT; C = D_; bx = id & 31; by = id >> 5; }
    const int tx = threadIdx.x & 31;
    const int ty = threadIdx.x >> 5;       // 0..7
    const int c0 = bx * 32;
    const int r0 = by * 32;
#pragma unroll
    for (int i = 0; i < 4; i++)
        tile[ty + i * 8][tx] = in[(size_t)(r0 + ty + i * 8) * C + c0 + tx];
    __syncthreads();
#pragma unroll
    for (int i = 0; i < 4; i++)
        out[(size_t)(c0 + ty + i * 8) * D_ + r0 + tx] = (__bf16)tile[tx][ty + i * 8];
}

// ------------------------- QKV GEMM, 256^2 pipelined -----------------------
// C[4096][3072] = A[4096][1024] @ Bt[3072][1024]^T + bias, scattered to
// Q (scaled) / K / Vt.  Schedule per K-tile kt (BK=64 = 2 ks-slices):
//   [issue Ak0(kt+1)] vmcnt(6) lgkm(0) barrier
//   read B(ks0); {read A half0; MFMA*16}; [issue Bk0(kt+1)]; {A half1; MFMA*16}
//   [issue Ak1(kt+1)] vmcnt(6) lgkm(0) barrier
//   read B(ks1); {A half0; MFMA*16}; [issue Bk1(kt+1)]; {A half1; MFMA*16}
// Steady state: 3 stages (6 loads) in flight across every barrier.

__global__ __launch_bounds__(512, 2) void qkv_gemm256_kernel(
    const __bf16* __restrict__ A, const __bf16* __restrict__ Bt,
    const float* __restrict__ bias,
    __bf16* __restrict__ Q, __bf16* __restrict__ Kb, __bf16* __restrict__ Vt) {
    constexpr int BM = 256, BN = 256;
    constexpr int K  = D_;                 // 1024
    constexpr int NK = K / 64;             // 16 K-tiles of 64 (2 ks-slices)
    constexpr int RP = BM + 8;             // vt tile row stride
    constexpr int SMEM_STAGE = 2 * 2 * (BM + BN) * 32 * 2;   // 131072
    constexpr int SMEM_VT    = BN * RP * 2;                  // 135168
    constexpr int SMEM_BYTES = SMEM_VT > SMEM_STAGE ? SMEM_VT : SMEM_STAGE;
    __shared__ __align__(16) char smem[SMEM_BYTES];
    __bf16* As = (__bf16*)smem;            // [2 buf][2 ks][256*32]
    __bf16* Bs = As + 4 * BM * 32;         // [2 buf][2 ks][256*32]

    const int tid  = threadIdx.x;
    const int lane = tid & 63;
    const int wave = tid >> 6;             // 0..7
    const int lo   = lane & 15;
    const int qd   = lane >> 4;
    const int wm   = (wave >> 2) * 128;    // wave M-origin (2 rows of waves)
    const int wn   = (wave & 3) * 64;      // wave N-origin (4 cols of waves)

    // bijective XCD swizzle: 192 blocks, 24 per XCD chunk (2 M-rows x 12 N)
    const int bidl = blockIdx.y * 12 + blockIdx.x;
    const int swz  = (bidl & 7) * 24 + (bidl >> 3);
    const int m0   = (swz / 12) * BM;
    const int n0   = (swz % 12) * BN;

    // staging decode (proven 128^2 pattern): chunk g -> LDS byte g*16;
    // row = g>>2, slot = g&3, global k-chunk = slot ^ ((row>>1)&3)
    const __bf16* gA[2];
    const __bf16* gB[2];
#pragma unroll
    for (int c = 0; c < 2; c++) {
        int g  = tid + 512 * c;            // 0..1023
        int cc = (g & 3) ^ ((g >> 3) & 3);
        gA[c] = A  + (size_t)(m0 + (g >> 2)) * K + cc * 8;
        gB[c] = Bt + (size_t)(n0 + (g >> 2)) * K + cc * 8;
    }

    auto stageA = [&](int buf, int ktn, int ks) {
        const int koff = ktn * 64 + ks * 32;
#pragma unroll
        for (int c = 0; c < 2; c++)
            GLOAD16(gA[c] + koff,
                    As + (buf * 2 + ks) * (BM * 32) + (tid + 512 * c) * 8);
    };
    auto stageB = [&](int buf, int ktn, int ks) {
        const int koff = ktn * 64 + ks * 32;
#pragma unroll
        for (int c = 0; c < 2; c++)
            GLOAD16(gB[c] + koff,
                    Bs + (buf * 2 + ks) * (BN * 32) + (tid + 512 * c) * 8);
    };

    f32x4 acc[8][4] = {};

    // prologue: tile 0's 4 stages in consumption order
    stageA(0, 0, 0); stageB(0, 0, 0); stageA(0, 0, 1); stageB(0, 0, 1);

    for (int kt = 0; kt < NK; kt++) {
        const int cur = kt & 1;
        const bool pf = (kt + 1 < NK);
        const __bf16* Ab = As + cur * 2 * (BM * 32);
        const __bf16* Bb = Bs + cur * 2 * (BN * 32);

        // ================= ks = 0 =================
        if (pf) { stageA(cur ^ 1, kt + 1, 0); WAIT_BAR(6); }
        else    { WAIT_BAR(4); }
        {
            bf16x8 bfr[4];
#pragma unroll
            for (int j = 0; j < 4; j++) {
                const int row = wn + j * 16 + lo;
                bfr[j] = *(const bf16x8*)(Bb + row * 32 +
                                          ((qd ^ ((row >> 1) & 3)) << 3));
            }
#pragma unroll
            for (int half = 0; half < 2; half++) {
                if (half == 1 && pf) stageB(cur ^ 1, kt + 1, 0);
                bf16x8 af[4];
#pragma unroll
                for (int ii = 0; ii < 4; ii++) {
                    const int row = wm + half * 64 + ii * 16 + lo;
                    af[ii] = *(const bf16x8*)(Ab + row * 32 +
                                              ((qd ^ ((row >> 1) & 3)) << 3));
                }
                __builtin_amdgcn_s_setprio(1);
#pragma unroll
                for (int ii = 0; ii < 4; ii++)
#pragma unroll
                    for (int j = 0; j < 4; j++)
                        acc[half * 4 + ii][j] =
                            MFMA16(af[ii], bfr[j], acc[half * 4 + ii][j]);
                __builtin_amdgcn_s_setprio(0);
            }
        }

        // ================= ks = 1 =================
        if (pf) { stageA(cur ^ 1, kt + 1, 1); WAIT_BAR(6); }
        else    { WAIT_BAR(0); }
        {
            const __bf16* Ab1 = Ab + BM * 32;
            const __bf16* Bb1 = Bb + BN * 32;
            bf16x8 bfr[4];
#pragma unroll
            for (int j = 0; j < 4; j++) {
                const int row = wn + j * 16 + lo;
                bfr[j] = *(const bf16x8*)(Bb1 + row * 32 +
                                          ((qd ^ ((row >> 1) & 3)) << 3));
            }
#pragma unroll
            for (int half = 0; half < 2; half++) {
                if (half == 1 && pf) stageB(cur ^ 1, kt + 1, 1);
                bf16x8 af[4];
#pragma unroll
                for (int ii = 0; ii < 4; ii++) {
                    const int row = wm + half * 64 + ii * 16 + lo;
                    af[ii] = *(const bf16x8*)(Ab1 + row * 32 +
                                              ((qd ^ ((row >> 1) & 3)) << 3));
                }
                __builtin_amdgcn_s_setprio(1);
#pragma unroll
                for (int ii = 0; ii < 4; ii++)
#pragma unroll
                    for (int j = 0; j < 4; j++)
                        acc[half * 4 + ii][j] =
                            MFMA16(af[ii], bfr[j], acc[half * 4 + ii][j]);
                __builtin_amdgcn_s_setprio(0);
            }
        }
    }

    if (n0 >= 2 * D_) {
        // ---- V region: LDS transpose tile -> coalesced Vt stores ----
        __bf16* vt = (__bf16*)smem;       // [BN gn-local][RP t-local]
        __syncthreads();                  // all staging reads/writes done
#pragma unroll
        for (int i = 0; i < 8; i++)
#pragma unroll
            for (int j = 0; j < 4; j++)
#pragma unroll
                for (int r = 0; r < 4; r++) {
                    const int lrow = wn + j * 16 + lo;         // gn-local
                    const int lcol = wm + i * 16 + qd * 4 + r; // t-local
                    vt[lrow * RP + lcol] =
                        (__bf16)(acc[i][j][r] + bias[n0 + lrow]);
                }
        __syncthreads();
        const int row = tid >> 1;          // 0..255 (gn-local)
        const int seg = tid & 1;           // 2 threads per row, 128 elems each
        const int gn  = n0 + row;
        const int bhv = ((m0 >> 11) << 4) + ((gn >> 6) & 15);
        const int dd  = gn & 63;
        __bf16* dst = Vt + ((size_t)bhv * DH_ + dd) * T_ + (m0 & (T_ - 1)) + seg * 128;
        const __bf16* src = vt + row * RP + seg * 128;
#pragma unroll
        for (int kk = 0; kk < 16; kk++)    // 16B stores
            *(uint4*)(dst + kk * 8) = *(const uint4*)(src + kk * 8);
        return;
    }

    // ---- Q/K region scatter ----
#pragma unroll
    for (int i = 0; i < 8; i++) {
#pragma unroll
        for (int j = 0; j < 4; j++) {
#pragma unroll
            for (int r = 0; r < 4; r++) {
                int gm = m0 + wm + i * 16 + qd * 4 + r;   // C/D row
                int gn = n0 + wn + j * 16 + lo;           // C/D col
                float v = acc[i][j][r] + bias[gn];
                int which = gn >> 10;                     // 0=q 1=k
                int bh = ((gm >> 11) << 4) + ((gn >> 6) & 15);
                int dd = gn & 63;
                int t  = gm & (T_ - 1);
                if (which == 0)
                    Q[((size_t)bh * T_ + t) * DH_ + dd] = (__bf16)(v * QSCALE);
                else
                    Kb[((size_t)bh * T_ + t) * DH_ + dd] = (__bf16)v;
            }
        }
    }
}

// ------------------------------- MFMA GEMM ---------------------------------
// (proj only now)  C[M][N] = A[M][K] @ Bt[N][K]^T + bias.  See R17 notes:
// 128x64 tiles, 3-deep LDS pipeline, vmcnt(loads-per-tile) waits, raw
// s_barrier, XOR-swizzled staging.  EPI 1: fp32 out + bias.

template <int EPI, int TM, int TN>
__global__ __launch_bounds__(256) void gemm_bt_kernel(
    const __bf16* __restrict__ A, const __bf16* __restrict__ Bt,
    const float* __restrict__ bias, float* __restrict__ Cout,
    __bf16* __restrict__ Q, __bf16* __restrict__ Kb, __bf16* __restrict__ Vt,
    int M, int N, int K) {
    constexpr int MI  = TM / 32;          // m-frags per wave
    constexpr int NJ  = TN / 32;          // n-frags per wave
    constexpr int WM  = MI * 16;          // rows per wave
    constexpr int WN  = NJ * 16;          // cols per wave
    constexpr int ACH = TM / 64;          // A-chunk rounds per thread
    constexpr int BCH = TN / 64;          // B-chunk rounds per thread
    constexpr int RP  = TM + 8;           // vt tile row stride (elems)
    constexpr int SMEM_STAGE = 3 * (TM + TN) * 32 * 2;
    constexpr int SMEM_VT    = (EPI == 0) ? TN * RP * 2 : 0;
    constexpr int SMEM_BYTES = SMEM_STAGE > SMEM_VT ? SMEM_STAGE : SMEM_VT;
    __shared__ __align__(16) char smem[SMEM_BYTES];
    __bf16* AsB = (__bf16*)smem;          // [3][TM*32]
    __bf16* BsB = AsB + 3 * TM * 32;      // [3][TN*32]

    const int tid  = threadIdx.x;
    const int lane = tid & 63;
    const int wave = tid >> 6;
    const int lo   = lane & 15;
    const int qd   = lane >> 4;
    const int wm   = (wave >> 1) * WM;
    const int wn   = (wave & 1) * WN;
    const int m0   = blockIdx.y * TM;
    const int n0   = blockIdx.x * TN;

    const __bf16* gA[ACH];
    const __bf16* gB[BCH];
#pragma unroll
    for (int c = 0; c < ACH; c++) {
        int g = tid + 256 * c;
        int cc = (g & 3) ^ ((g >> 3) & 3);
        gA[c] = A + (size_t)(m0 + (g >> 2)) * K + cc * 8;
    }
#pragma unroll
    for (int c = 0; c < BCH; c++) {
        int g = tid + 256 * c;
        int cc = (g & 3) ^ ((g >> 3) & 3);
        gB[c] = Bt + (size_t)(n0 + (g >> 2)) * K + cc * 8;
    }

    f32x4 acc[MI][NJ] = {};
    const int nk = K >> 5;

    // prologue: stage tiles 0 and 1 (2-deep)
#pragma unroll
    for (int pb = 0; pb < 2; pb++) {
        const int k0 = pb << 5;
#pragma unroll
        for (int c = 0; c < ACH; c++)
            GLOAD16(gA[c] + k0, AsB + pb * TM * 32 + (tid + 256 * c) * 8);
#pragma unroll
        for (int c = 0; c < BCH; c++)
            GLOAD16(gB[c] + k0, BsB + pb * TN * 32 + (tid + 256 * c) * 8);
    }

    for (int kt = 0; kt < nk; kt++) {
        const int cur = kt % 3;
        if (kt + 1 < nk) {
            __asm__ volatile("s_waitcnt vmcnt(%0) lgkmcnt(0)" ::
                             "i"(ACH + BCH) : "memory");
        } else {
            __asm__ volatile("s_waitcnt vmcnt(0) lgkmcnt(0)" ::: "memory");
        }
        __asm__ volatile("s_barrier" ::: "memory");
        if (kt + 2 < nk) {
            const int k0n = (kt + 2) << 5;
            const int nb  = (kt + 2) % 3;
#pragma unroll
            for (int c = 0; c < ACH; c++)
                GLOAD16(gA[c] + k0n, AsB + nb * TM * 32 + (tid + 256 * c) * 8);
#pragma unroll
            for (int c = 0; c < BCH; c++)
                GLOAD16(gB[c] + k0n, BsB + nb * TN * 32 + (tid + 256 * c) * 8);
        }
        bf16x8 af[MI], bfr[NJ];
#pragma unroll
        for (int i = 0; i < MI; i++) {
            const int row = wm + i * 16 + lo;
            af[i] = *(const bf16x8*)(AsB + cur * TM * 32 + row * 32 +
                                     ((qd ^ ((row >> 1) & 3)) << 3));
        }
#pragma unroll
        for (int j = 0; j < NJ; j++) {
            const int row = wn + j * 16 + lo;
            bfr[j] = *(const bf16x8*)(BsB + cur * TN * 32 + row * 32 +
                                      ((qd ^ ((row >> 1) & 3)) << 3));
        }
#pragma unroll
        for (int i = 0; i < MI; i++)
#pragma unroll
            for (int j = 0; j < NJ; j++)
                acc[i][j] = MFMA16(af[i], bfr[j], acc[i][j]);
    }

    if (EPI == 0 && n0 >= 2 * D_) {
        __bf16* vt = (__bf16*)smem;
        __syncthreads();
#pragma unroll
        for (int i = 0; i < MI; i++)
#pragma unroll
            for (int j = 0; j < NJ; j++)
#pragma unroll
                for (int r = 0; r < 4; r++) {
                    const int lrow = wn + j * 16 + lo;
                    const int lcol = wm + i * 16 + qd * 4 + r;
                    vt[lrow * RP + lcol] =
                        (__bf16)(acc[i][j][r] + bias[n0 + lrow]);
                }
        __syncthreads();
        constexpr int TPR = 256 / TN;
        constexpr int SEG = TM / TPR;
        const int row = tid / TPR;
        const int seg = tid % TPR;
        const int gn  = n0 + row;
        const int bhv = ((m0 >> 11) << 4) + ((gn >> 6) & 15);
        const int dd  = gn & 63;
        __bf16* dst = Vt + ((size_t)bhv * DH_ + dd) * T_ + (m0 & (T_ - 1)) + seg * SEG;
        const __bf16* src = vt + row * RP + seg * SEG;
#pragma unroll
        for (int kk = 0; kk < SEG / 8; kk++)
            *(uint4*)(dst + kk * 8) = *(const uint4*)(src + kk * 8);
        return;
    }

#pragma unroll
    for (int i = 0; i < MI; i++) {
#pragma unroll
        for (int j = 0; j < NJ; j++) {
#pragma unroll
            for (int r = 0; r < 4; r++) {
                int gm = m0 + wm + i * 16 + qd * 4 + r;
                int gn = n0 + wn + j * 16 + lo;
                float v = acc[i][j][r] + bias[gn];
                if (EPI == 1) {
                    Cout[(size_t)gm * N + gn] = v;
                } else {
                    int which = gn >> 10;
                    int bh = ((gm >> 11) << 4) + ((gn >> 6) & 15);
                    int dd = gn & 63;
                    int t  = gm & (T_ - 1);
                    if (which == 0)
                        Q[((size_t)bh * T_ + t) * DH_ + dd] = (__bf16)(v * QSCALE);
                    else
                        Kb[((size_t)bh * T_ + t) * DH_ + dd] = (__bf16)v;
                }
            }
        }
    }
}

// ---------------------------- flash attention ------------------------------
// R20 kernel (frozen).  Grid 1024, 4 blocks/CU (32KB LDS), balanced
// quadruple item map, heads XCD-pinned, K/V dbuf + prefetch, XOR-swizzled,
// fixed m=0 softmax, MFMA ones-trick row sums, in-register softmax via
// swapped QK^T + cvt_pk_bf16 + permlane swaps, setprio around MFMA.

__global__ __launch_bounds__(256) void attn_kernel(
    const __bf16* __restrict__ Q,   // [BH][T][64], pre-scaled
    const __bf16* __restrict__ Kb,  // [BH][T][64]
    const __bf16* __restrict__ Vt,  // [BH][64][T]
    __bf16* __restrict__ O) {       // [B][T][H*64]
    __shared__ __bf16 Ks[2][64 * 64];     // [key][d]  2 x 8 KB, swizzled
    __shared__ __bf16 Vs[2][64 * 64];     // [d][key]  2 x 8 KB, swizzled

    const int tid  = threadIdx.x;
    const int wave = tid >> 6;
    const int lane = tid & 63;
    const int lo   = lane & 15;
    const int qd   = lane >> 4;

    const int g0  = wave * 128 + lane;
    const int g1  = g0 + 64;
    const int r0s = g0 >> 3, c0s = (g0 & 7) ^ (r0s & 7);
    const int r1s = g1 >> 3, c1s = (g1 & 7) ^ (r1s & 7);
    const int so0 = wave * 1024;
    const int so1 = wave * 1024 + 512;

    bf16x8 ones;
#pragma unroll
    for (int i = 0; i < 8; i++) ones[i] = (__bf16)1.0f;

    const int k  = blockIdx.x;            // 0..1023
    const int j  = k >> 5;                // 0..31
    const int bh = k & 31;
    int x;
    if (j < 8)       x = 31 - j;
    else if (j < 16) x = j - 8;
    else if (j < 24) x = 39 - j;
    else             x = j - 16;

    const int b    = bh >> 4;
    const int h    = bh & 15;
    const int q0   = x * 64 + wave * 16;

    const __bf16* Qh = Q + (size_t)bh * T_ * DH_;
    const __bf16* Kh = Kb + (size_t)bh * T_ * DH_;
    const __bf16* Vh = Vt + (size_t)bh * DH_ * T_;

    bf16x8 qa0 = *(const bf16x8*)(Qh + (size_t)(q0 + lo) * DH_ + qd * 8);
    bf16x8 qa1 = *(const bf16x8*)(Qh + (size_t)(q0 + lo) * DH_ + 32 + qd * 8);

    f32x4 oacc[4] = {};
    float lrow[4] = {0.0f, 0.0f, 0.0f, 0.0f};
    const int qrow  = q0 + qd * 4;
    const int ntile = x + 1;

    GLOAD16(Kh + (size_t)r0s * DH_ + c0s * 8, Ks[0] + so0);
    GLOAD16(Kh + (size_t)r1s * DH_ + c1s * 8, Ks[0] + so1);
    GLOAD16(Vh + (size_t)r0s * T_ + c0s * 8, Vs[0] + so0);
    GLOAD16(Vh + (size_t)r1s * T_ + c1s * 8, Vs[0] + so1);
    DRAIN_ALL();
    __syncthreads();

    for (int t = 0; t < ntile; t++) {
        const int j0  = t << 6;
        const int cur = t & 1;
        if (t + 1 < ntile) {
            const int j0n = j0 + 64;
            GLOAD16(Kh + (size_t)(j0n + r0s) * DH_ + c0s * 8, Ks[1 - cur] + so0);
            GLOAD16(Kh + (size_t)(j0n + r1s) * DH_ + c1s * 8, Ks[1 - cur] + so1);
            GLOAD16(Vh + (size_t)r0s * T_ + j0n + c0s * 8, Vs[1 - cur] + so0);
            GLOAD16(Vh + (size_t)r1s * T_ + j0n + c1s * 8, Vs[1 - cur] + so1);
        }

        // ---- S^T = K @ Q^T: lane (lo,qd) holds S[q=lo][key=16g+4qd+r] ----
        f32x4 s[4] = {};
        __builtin_amdgcn_s_setprio(1);
#pragma unroll
        for (int g = 0; g < 4; g++) {
            const int row = g * 16 + lo;
            const __bf16* kr = Ks[cur] + row * 64;
            bf16x8 kb0 = *(const bf16x8*)(kr + ((qd ^ (row & 7)) << 3));
            bf16x8 kb1 = *(const bf16x8*)(kr + (((4 + qd) ^ (row & 7)) << 3));
            s[g] = MFMA16(kb0, qa0, s[g]);
            s[g] = MFMA16(kb1, qa1, s[g]);
        }
        __builtin_amdgcn_s_setprio(0);

        if (j0 + 63 > q0) {
            const int qg = q0 + lo;
#pragma unroll
            for (int g = 0; g < 4; g++) {
                const int kbase = j0 + g * 16 + qd * 4;
#pragma unroll
                for (int r = 0; r < 4; r++)
                    s[g][r] = (kbase + r <= qg) ? s[g][r] : -1e30f;
            }
        }

        // ---- P = exp2(S), packed to bf16 pairs in-register ----
        unsigned Aw[4], Bw[4];
#pragma unroll
        for (int g = 0; g < 4; g++) {
            float p0 = __builtin_amdgcn_exp2f(s[g][0]);
            float p1 = __builtin_amdgcn_exp2f(s[g][1]);
            float p2 = __builtin_amdgcn_exp2f(s[g][2]);
            float p3 = __builtin_amdgcn_exp2f(s[g][3]);
            __asm__("v_cvt_pk_bf16_f32 %0, %1, %2" : "=v"(Aw[g]) : "v"(p0), "v"(p1));
            __asm__("v_cvt_pk_bf16_f32 %0, %1, %2" : "=v"(Bw[g]) : "v"(p2), "v"(p3));
        }
        xpose_pair(Aw[0], Aw[1]);
        xpose_pair(Bw[0], Bw[1]);
        xpose_pair(Aw[2], Aw[3]);
        xpose_pair(Bw[2], Bw[3]);
        u32x4 P0 = {Aw[0], Bw[0], Aw[1], Bw[1]};   // keys  0..31
        u32x4 P1 = {Aw[2], Bw[2], Aw[3], Bw[3]};   // keys 32..63
        bf16x8 pa0 = __builtin_bit_cast(bf16x8, P0);
        bf16x8 pa1 = __builtin_bit_cast(bf16x8, P1);

        // ---- row sums via MFMA ones-trick + O += P @ V ----
        f32x4 ps = {};
        __builtin_amdgcn_s_setprio(1);
        ps = MFMA16(pa0, ones, ps);
        ps = MFMA16(pa1, ones, ps);
#pragma unroll
        for (int c = 0; c < 4; c++) {
            const int row = c * 16 + lo;
            const __bf16* vr = Vs[cur] + row * 64;
            bf16x8 vb0 = *(const bf16x8*)(vr + ((qd ^ (row & 7)) << 3));
            bf16x8 vb1 = *(const bf16x8*)(vr + (((4 + qd) ^ (row & 7)) << 3));
            oacc[c] = MFMA16(pa0, vb0, oacc[c]);
            oacc[c] = MFMA16(pa1, vb1, oacc[c]);
        }
        __builtin_amdgcn_s_setprio(0);
#pragma unroll
        for (int r = 0; r < 4; r++) lrow[r] += ps[r];

        DRAIN_ALL();
        __syncthreads();
    }

    float inv[4];
#pragma unroll
    for (int r = 0; r < 4; r++) inv[r] = 1.0f / lrow[r];
#pragma unroll
    for (int c = 0; c < 4; c++) {
#pragma unroll
        for (int r = 0; r < 4; r++) {
            float val = oacc[c][r] * inv[r];
            size_t idx = ((size_t)b * T_ + (qrow + r)) * D_ + h * DH_ + c * 16 + lo;
            O[idx] = (__bf16)val;
        }
    }
}

// -------------------------------- launcher ---------------------------------

extern "C" void kernel_launch(void* const* d_in, const int* in_sizes, int n_in,
                              void* d_out, int out_size, void* d_ws, size_t ws_size,
                              hipStream_t stream) {
    const float* x      = (const float*)d_in[0];
    const float* w_attn = (const float*)d_in[1];
    const float* b_attn = (const float*)d_in[2];
    const float* w_proj = (const float*)d_in[3];
    const float* b_proj = (const float*)d_in[4];
    float* out = (float*)d_out;

    const size_t MB = (size_t)1 << 20;
    if (ws_size < 48 * MB) return;   // need 48 MB scratch

    char* ws = (char*)d_ws;
    __bf16* xb     = (__bf16*)(ws);              //  8 MB  [M][D]
    __bf16* wattnT = (__bf16*)(ws + 8 * MB);     //  6 MB  [3D][D]
    __bf16* wprojT = (__bf16*)(ws + 14 * MB);    //  2 MB  [D][D]
    __bf16* Qb     = (__bf16*)(ws + 16 * MB);    //  8 MB  [BH][T][64]
    __bf16* Kb     = (__bf16*)(ws + 24 * MB);    //  8 MB  [BH][T][64]
    __bf16* Vt     = (__bf16*)(ws + 32 * MB);    //  8 MB  [BH][64][T]
    __bf16* Ob     = (__bf16*)(ws + 40 * MB);    //  8 MB  [M][D]

    // 1. fused prep: x convert + both weight transposes
    prep_kernel<<<dim3(8192), 256, 0, stream>>>(x, xb, w_attn, wattnT,
                                                w_proj, wprojT);
    // 2. QKV GEMM -> Q(scaled)/K/Vt  (256x256 tiles, deep pipeline)
    qkv_gemm256_kernel<<<dim3(12, 16), 512, 0, stream>>>(
        xb, wattnT, b_attn, Qb, Kb, Vt);
    // 3. causal flash attention (1024 blocks, 4/CU, in-register softmax)
    attn_kernel<<<dim3(1024), 256, 0, stream>>>(Qb, Kb, Vt, Ob);
    // 4. output projection (fp32 + bias), 128x64 tiles -> 512 blocks
    gemm_bt_kernel<1, 128, 64><<<dim3(D_ / 64, M_ / 128), 256, 0, stream>>>(
        Ob, wprojT, b_proj, out, nullptr, nullptr, nullptr, M_, D_, D_);
}

// Round 3
// 171.740 us; speedup vs baseline: 1.0489x; 1.0001x over previous
//
#include <hip/hip_runtime.h>

// ---------------------------------------------------------------------------
// FlashAttention block: out = proj(causal_attn(qkv(x)))
// B=2, T=2048, D=1024, H=16, dhead=64.  All GEMMs + attention in bf16 MFMA
// (16x16x32), fp32 accumulate.  fp32 output.
// R22 = R21 with the QKV 256^2 main loop restructured from a coarse 2-phase
// split into the m201-style FINE 4-phase interleave (m196: the per-phase
// ds_read||G-load||MFMA interleave is the lever; coarse split without it
// loses 7-27%):
//   - phase = (ks-slice, m-half): {4-8 ds_read_b128 for this quadrant only;
//     issue exactly 1 staging slot of tile t+1; lgkmcnt(0); setprio(1);
//     16 MFMA; setprio(0); s_barrier}.
//   - visibility skeleton UNCHANGED from R21 (verified): WAIT_BAR(6) at
//     phases 1 and 3 retires exactly {sA0,sB0} / {sA1,sB1} of the current
//     tile; 6 loads stay in flight across every barrier (T4); every LDS
//     slot rewrite is >=3 barriers after its last reader.
//   - B-frags persist in registers across the two m-half phases (no re-read).
// attn: R20 kernel (in-register softmax via swapped QK^T + cvt_pk +
// permlane swaps, 32KB LDS, setprio).  proj GEMM + prep unchanged.
// ---------------------------------------------------------------------------

#define B_   2
#define T_   2048
#define D_   1024
#define H_   16
#define DH_  64
#define M_   (B_ * T_)       // 4096
#define N1_  (3 * D_)        // 3072
// qscale folds 1/sqrt(dhead) and log2(e) so softmax uses native exp2
#define QSCALE (0.125f * 1.44269504088896340736f)

typedef __bf16 bf16x8 __attribute__((ext_vector_type(8)));
typedef __bf16 bf16x4 __attribute__((ext_vector_type(4)));
typedef float  f32x4  __attribute__((ext_vector_type(4)));
typedef int    i32x2  __attribute__((ext_vector_type(2)));
typedef unsigned u32x4 __attribute__((ext_vector_type(4)));

#define MFMA16(a, b, c) __builtin_amdgcn_mfma_f32_16x16x32_bf16((a), (b), (c), 0, 0, 0)

// async global->LDS, 16B per lane; LDS dest = base + lane*16 (wave-uniform base)
#define GLOAD16(gp, lp)                                                        \
    __builtin_amdgcn_global_load_lds(                                          \
        (const __attribute__((address_space(1))) void*)(gp),                   \
        (__attribute__((address_space(3))) void*)(lp), 16, 0, 0)

#define DRAIN_ALL() __asm__ volatile("s_waitcnt vmcnt(0) lgkmcnt(0)" ::: "memory")

// drain own VMEM to N, drain all DS, then barrier (single asm so the drain
// provably precedes the barrier regardless of scheduling)
#define WAIT_BAR(N)                                                            \
    __asm__ volatile("s_waitcnt vmcnt(" #N ") lgkmcnt(0)\n\ts_barrier" ::: "memory")

#define LGKM0() __asm__ volatile("s_waitcnt lgkmcnt(0)" ::: "memory")
#define BAR()   __asm__ volatile("s_barrier" ::: "memory")

#if defined(__has_builtin)
#if __has_builtin(__builtin_amdgcn_permlane32_swap) && \
    __has_builtin(__builtin_amdgcn_permlane16_swap)
#define HAVE_PERMLANE_SWAP 1
#endif
#endif

// Transpose step for the in-register P-fragment rebuild (see attn_kernel).
__device__ __forceinline__ void xpose_pair(unsigned& a, unsigned& b) {
#if defined(HAVE_PERMLANE_SWAP)
    i32x2 r1 = __builtin_amdgcn_permlane32_swap((int)a, (int)b, false, false);
    i32x2 r2 = __builtin_amdgcn_permlane16_swap(r1[0], r1[1], false, false);
    a = (unsigned)r2[0];
    b = (unsigned)r2[1];
#else
    const int lane = threadIdx.x & 63;
    const int lo   = lane & 15;
    const int srcE = lo + 32 * ((lane >> 4) & 1);
    const int srcO = srcE + 16;
    int aE = __shfl((int)a, srcE, 64), bE = __shfl((int)b, srcE, 64);
    int aO = __shfl((int)a, srcO, 64), bO = __shfl((int)b, srcO, 64);
    unsigned w0 = (lane & 32) ? (unsigned)bE : (unsigned)aE;
    unsigned w2 = (lane & 32) ? (unsigned)bO : (unsigned)aO;
    a = w0;
    b = w2;
#endif
}

// ------------------------------ fused prep ---------------------------------

__global__ __launch_bounds__(256) void prep_kernel(
    const float* __restrict__ x,      __bf16* __restrict__ xb,
    const float* __restrict__ w_attn, __bf16* __restrict__ wattnT,
    const float* __restrict__ w_proj, __bf16* __restrict__ wprojT) {
    __shared__ float tile[32][33];
    int id = blockIdx.x;
    if (id < 4096) {                       // x convert
        int i = (id * 256 + threadIdx.x) * 4;
        float4 f = *(const float4*)(x + i);
        bf16x4 o;
        o[0] = (__bf16)f.x; o[1] = (__bf16)f.y; o[2] = (__bf16)f.z; o[3] = (__bf16)f.w;
        *(bf16x4*)(xb + i) = o;
        return;
    }
    id -= 4096;
    const float* in;
    __bf16* out;
    int C, bx, by;
    if (id < 3072) { in = w_attn; out = wattnT; C = N1_; bx = id % 96; by = id / 96; }
    else { id -= 3072; in = w_proj; out = wprojT; C = D_; bx = id & 31; by = id >> 5; }
    const int tx = threadIdx.x & 31;
    const int ty = threadIdx.x >> 5;       // 0..7
    const int c0 = bx * 32;
    const int r0 = by * 32;
#pragma unroll
    for (int i = 0; i < 4; i++)
        tile[ty + i * 8][tx] = in[(size_t)(r0 + ty + i * 8) * C + c0 + tx];
    __syncthreads();
#pragma unroll
    for (int i = 0; i < 4; i++)
        out[(size_t)(c0 + ty + i * 8) * D_ + r0 + tx] = (__bf16)tile[tx][ty + i * 8];
}

// ------------------------- QKV GEMM, 256^2 pipelined -----------------------
// C[4096][3072] = A[4096][1024] @ Bt[3072][1024]^T + bias, scattered to
// Q (scaled) / K / Vt.  Fine 4-phase schedule per K-tile kt (BK=64):
//   ph1 (ks0,mh0): [issue sA0(kt+1)] WAIT_BAR(6); read B0(4)+A0h0(4);
//                  lgkm0; prio1; 16 MFMA; prio0; bar
//   ph2 (ks0,mh1): [issue sB0(kt+1)]; read A0h1(4); lgkm0; 16 MFMA; bar
//   ph3 (ks1,mh0): [issue sA1(kt+1)] WAIT_BAR(6); read B1(4)+A1h0(4);
//                  lgkm0; 16 MFMA; bar
//   ph4 (ks1,mh1): [issue sB1(kt+1)]; read A1h1(4); lgkm0; 16 MFMA; bar
// Steady state: 3 stages (6 loads) in flight across every barrier.

__global__ __launch_bounds__(512, 2) void qkv_gemm256_kernel(
    const __bf16* __restrict__ A, const __bf16* __restrict__ Bt,
    const float* __restrict__ bias,
    __bf16* __restrict__ Q, __bf16* __restrict__ Kb, __bf16* __restrict__ Vt) {
    constexpr int BM = 256, BN = 256;
    constexpr int K  = D_;                 // 1024
    constexpr int NK = K / 64;             // 16 K-tiles of 64 (2 ks-slices)
    constexpr int RP = BM + 8;             // vt tile row stride
    constexpr int SMEM_STAGE = 2 * 2 * (BM + BN) * 32 * 2;   // 131072
    constexpr int SMEM_VT    = BN * RP * 2;                  // 135168
    constexpr int SMEM_BYTES = SMEM_VT > SMEM_STAGE ? SMEM_VT : SMEM_STAGE;
    __shared__ __align__(16) char smem[SMEM_BYTES];
    __bf16* As = (__bf16*)smem;            // [2 buf][2 ks][256*32]
    __bf16* Bs = As + 4 * BM * 32;         // [2 buf][2 ks][256*32]

    const int tid  = threadIdx.x;
    const int lane = tid & 63;
    const int wave = tid >> 6;             // 0..7
    const int lo   = lane & 15;
    const int qd   = lane >> 4;
    const int wm   = (wave >> 2) * 128;    // wave M-origin (2 rows of waves)
    const int wn   = (wave & 3) * 64;      // wave N-origin (4 cols of waves)

    // bijective XCD swizzle: 192 blocks, 24 per XCD chunk (2 M-rows x 12 N)
    const int bidl = blockIdx.y * 12 + blockIdx.x;
    const int swz  = (bidl & 7) * 24 + (bidl >> 3);
    const int m0   = (swz / 12) * BM;
    const int n0   = (swz % 12) * BN;

    // staging decode (proven 128^2 pattern): chunk g -> LDS byte g*16;
    // row = g>>2, slot = g&3, global k-chunk = slot ^ ((row>>1)&3)
    const __bf16* gA[2];
    const __bf16* gB[2];
#pragma unroll
    for (int c = 0; c < 2; c++) {
        int g  = tid + 512 * c;            // 0..1023
        int cc = (g & 3) ^ ((g >> 3) & 3);
        gA[c] = A  + (size_t)(m0 + (g >> 2)) * K + cc * 8;
        gB[c] = Bt + (size_t)(n0 + (g >> 2)) * K + cc * 8;
    }

    auto stageA = [&](int buf, int ktn, int ks) {
        const int koff = ktn * 64 + ks * 32;
#pragma unroll
        for (int c = 0; c < 2; c++)
            GLOAD16(gA[c] + koff,
                    As + (buf * 2 + ks) * (BM * 32) + (tid + 512 * c) * 8);
    };
    auto stageB = [&](int buf, int ktn, int ks) {
        const int koff = ktn * 64 + ks * 32;
#pragma unroll
        for (int c = 0; c < 2; c++)
            GLOAD16(gB[c] + koff,
                    Bs + (buf * 2 + ks) * (BN * 32) + (tid + 512 * c) * 8);
    };

    f32x4 acc[8][4] = {};

    // prologue: tile 0's 4 stages in consumption order
    stageA(0, 0, 0); stageB(0, 0, 0); stageA(0, 0, 1); stageB(0, 0, 1);

    for (int kt = 0; kt < NK; kt++) {
        const int cur = kt & 1;
        const int nxt = cur ^ 1;
        const bool pf = (kt + 1 < NK);
        const __bf16* A0 = As + cur * 2 * (BM * 32);   // ks0 slice
        const __bf16* A1 = A0 + BM * 32;               // ks1 slice
        const __bf16* B0 = Bs + cur * 2 * (BN * 32);
        const __bf16* B1 = B0 + BN * 32;
        bf16x8 af[4], bfr[4];

        // ---------- phase 1: (ks0, m-half0) ----------
        if (pf) { stageA(nxt, kt + 1, 0); WAIT_BAR(6); }
        else    { WAIT_BAR(4); }
#pragma unroll
        for (int j = 0; j < 4; j++) {
            const int row = wn + j * 16 + lo;
            bfr[j] = *(const bf16x8*)(B0 + row * 32 + ((qd ^ ((row >> 1) & 3)) << 3));
        }
#pragma unroll
        for (int ii = 0; ii < 4; ii++) {
            const int row = wm + ii * 16 + lo;
            af[ii] = *(const bf16x8*)(A0 + row * 32 + ((qd ^ ((row >> 1) & 3)) << 3));
        }
        LGKM0();
        __builtin_amdgcn_s_setprio(1);
#pragma unroll
        for (int ii = 0; ii < 4; ii++)
#pragma unroll
            for (int j = 0; j < 4; j++)
                acc[ii][j] = MFMA16(af[ii], bfr[j], acc[ii][j]);
        __builtin_amdgcn_s_setprio(0);
        BAR();

        // ---------- phase 2: (ks0, m-half1) ----------
        if (pf) stageB(nxt, kt + 1, 0);
#pragma unroll
        for (int ii = 0; ii < 4; ii++) {
            const int row = wm + 64 + ii * 16 + lo;
            af[ii] = *(const bf16x8*)(A0 + row * 32 + ((qd ^ ((row >> 1) & 3)) << 3));
        }
        LGKM0();
        __builtin_amdgcn_s_setprio(1);
#pragma unroll
        for (int ii = 0; ii < 4; ii++)
#pragma unroll
            for (int j = 0; j < 4; j++)
                acc[4 + ii][j] = MFMA16(af[ii], bfr[j], acc[4 + ii][j]);
        __builtin_amdgcn_s_setprio(0);
        BAR();

        // ---------- phase 3: (ks1, m-half0) ----------
        if (pf) { stageA(nxt, kt + 1, 1); WAIT_BAR(6); }
        else    { WAIT_BAR(0); }
#pragma unroll
        for (int j = 0; j < 4; j++) {
            const int row = wn + j * 16 + lo;
            bfr[j] = *(const bf16x8*)(B1 + row * 32 + ((qd ^ ((row >> 1) & 3)) << 3));
        }
#pragma unroll
        for (int ii = 0; ii < 4; ii++) {
            const int row = wm + ii * 16 + lo;
            af[ii] = *(const bf16x8*)(A1 + row * 32 + ((qd ^ ((row >> 1) & 3)) << 3));
        }
        LGKM0();
        __builtin_amdgcn_s_setprio(1);
#pragma unroll
        for (int ii = 0; ii < 4; ii++)
#pragma unroll
            for (int j = 0; j < 4; j++)
                acc[ii][j] = MFMA16(af[ii], bfr[j], acc[ii][j]);
        __builtin_amdgcn_s_setprio(0);
        BAR();

        // ---------- phase 4: (ks1, m-half1) ----------
        if (pf) stageB(nxt, kt + 1, 1);
#pragma unroll
        for (int ii = 0; ii < 4; ii++) {
            const int row = wm + 64 + ii * 16 + lo;
            af[ii] = *(const bf16x8*)(A1 + row * 32 + ((qd ^ ((row >> 1) & 3)) << 3));
        }
        LGKM0();
        __builtin_amdgcn_s_setprio(1);
#pragma unroll
        for (int ii = 0; ii < 4; ii++)
#pragma unroll
            for (int j = 0; j < 4; j++)
                acc[4 + ii][j] = MFMA16(af[ii], bfr[j], acc[4 + ii][j]);
        __builtin_amdgcn_s_setprio(0);
        BAR();
    }

    if (n0 >= 2 * D_) {
        // ---- V region: LDS transpose tile -> coalesced Vt stores ----
        __bf16* vt = (__bf16*)smem;       // [BN gn-local][RP t-local]
        __syncthreads();                  // all staging reads/writes done
#pragma unroll
        for (int i = 0; i < 8; i++)
#pragma unroll
            for (int j = 0; j < 4; j++)
#pragma unroll
                for (int r = 0; r < 4; r++) {
                    const int lrow = wn + j * 16 + lo;         // gn-local
                    const int lcol = wm + i * 16 + qd * 4 + r; // t-local
                    vt[lrow * RP + lcol] =
                        (__bf16)(acc[i][j][r] + bias[n0 + lrow]);
                }
        __syncthreads();
        const int row = tid >> 1;          // 0..255 (gn-local)
        const int seg = tid & 1;           // 2 threads per row, 128 elems each
        const int gn  = n0 + row;
        const int bhv = ((m0 >> 11) << 4) + ((gn >> 6) & 15);
        const int dd  = gn & 63;
        __bf16* dst = Vt + ((size_t)bhv * DH_ + dd) * T_ + (m0 & (T_ - 1)) + seg * 128;
        const __bf16* src = vt + row * RP + seg * 128;
#pragma unroll
        for (int kk = 0; kk < 16; kk++)    // 16B stores
            *(uint4*)(dst + kk * 8) = *(const uint4*)(src + kk * 8);
        return;
    }

    // ---- Q/K region scatter ----
#pragma unroll
    for (int i = 0; i < 8; i++) {
#pragma unroll
        for (int j = 0; j < 4; j++) {
#pragma unroll
            for (int r = 0; r < 4; r++) {
                int gm = m0 + wm + i * 16 + qd * 4 + r;   // C/D row
                int gn = n0 + wn + j * 16 + lo;           // C/D col
                float v = acc[i][j][r] + bias[gn];
                int which = gn >> 10;                     // 0=q 1=k
                int bh = ((gm >> 11) << 4) + ((gn >> 6) & 15);
                int dd = gn & 63;
                int t  = gm & (T_ - 1);
                if (which == 0)
                    Q[((size_t)bh * T_ + t) * DH_ + dd] = (__bf16)(v * QSCALE);
                else
                    Kb[((size_t)bh * T_ + t) * DH_ + dd] = (__bf16)v;
            }
        }
    }
}

// ------------------------------- MFMA GEMM ---------------------------------
// (proj only now)  C[M][N] = A[M][K] @ Bt[N][K]^T + bias.  128x64 tiles,
// 3-deep LDS pipeline, vmcnt(loads-per-tile) waits, raw s_barrier,
// XOR-swizzled staging.  EPI 1: fp32 out + bias.

template <int EPI, int TM, int TN>
__global__ __launch_bounds__(256) void gemm_bt_kernel(
    const __bf16* __restrict__ A, const __bf16* __restrict__ Bt,
    const float* __restrict__ bias, float* __restrict__ Cout,
    __bf16* __restrict__ Q, __bf16* __restrict__ Kb, __bf16* __restrict__ Vt,
    int M, int N, int K) {
    constexpr int MI  = TM / 32;          // m-frags per wave
    constexpr int NJ  = TN / 32;          // n-frags per wave
    constexpr int WM  = MI * 16;          // rows per wave
    constexpr int WN  = NJ * 16;          // cols per wave
    constexpr int ACH = TM / 64;          // A-chunk rounds per thread
    constexpr int BCH = TN / 64;          // B-chunk rounds per thread
    constexpr int RP  = TM + 8;           // vt tile row stride (elems)
    constexpr int SMEM_STAGE = 3 * (TM + TN) * 32 * 2;
    constexpr int SMEM_VT    = (EPI == 0) ? TN * RP * 2 : 0;
    constexpr int SMEM_BYTES = SMEM_STAGE > SMEM_VT ? SMEM_STAGE : SMEM_VT;
    __shared__ __align__(16) char smem[SMEM_BYTES];
    __bf16* AsB = (__bf16*)smem;          // [3][TM*32]
    __bf16* BsB = AsB + 3 * TM * 32;      // [3][TN*32]

    const int tid  = threadIdx.x;
    const int lane = tid & 63;
    const int wave = tid >> 6;
    const int lo   = lane & 15;
    const int qd   = lane >> 4;
    const int wm   = (wave >> 1) * WM;
    const int wn   = (wave & 1) * WN;
    const int m0   = blockIdx.y * TM;
    const int n0   = blockIdx.x * TN;

    const __bf16* gA[ACH];
    const __bf16* gB[BCH];
#pragma unroll
    for (int c = 0; c < ACH; c++) {
        int g = tid + 256 * c;
        int cc = (g & 3) ^ ((g >> 3) & 3);
        gA[c] = A + (size_t)(m0 + (g >> 2)) * K + cc * 8;
    }
#pragma unroll
    for (int c = 0; c < BCH; c++) {
        int g = tid + 256 * c;
        int cc = (g & 3) ^ ((g >> 3) & 3);
        gB[c] = Bt + (size_t)(n0 + (g >> 2)) * K + cc * 8;
    }

    f32x4 acc[MI][NJ] = {};
    const int nk = K >> 5;

    // prologue: stage tiles 0 and 1 (2-deep)
#pragma unroll
    for (int pb = 0; pb < 2; pb++) {
        const int k0 = pb << 5;
#pragma unroll
        for (int c = 0; c < ACH; c++)
            GLOAD16(gA[c] + k0, AsB + pb * TM * 32 + (tid + 256 * c) * 8);
#pragma unroll
        for (int c = 0; c < BCH; c++)
            GLOAD16(gB[c] + k0, BsB + pb * TN * 32 + (tid + 256 * c) * 8);
    }

    for (int kt = 0; kt < nk; kt++) {
        const int cur = kt % 3;
        if (kt + 1 < nk) {
            __asm__ volatile("s_waitcnt vmcnt(%0) lgkmcnt(0)" ::
                             "i"(ACH + BCH) : "memory");
        } else {
            __asm__ volatile("s_waitcnt vmcnt(0) lgkmcnt(0)" ::: "memory");
        }
        __asm__ volatile("s_barrier" ::: "memory");
        if (kt + 2 < nk) {
            const int k0n = (kt + 2) << 5;
            const int nb  = (kt + 2) % 3;
#pragma unroll
            for (int c = 0; c < ACH; c++)
                GLOAD16(gA[c] + k0n, AsB + nb * TM * 32 + (tid + 256 * c) * 8);
#pragma unroll
            for (int c = 0; c < BCH; c++)
                GLOAD16(gB[c] + k0n, BsB + nb * TN * 32 + (tid + 256 * c) * 8);
        }
        bf16x8 af[MI], bfr[NJ];
#pragma unroll
        for (int i = 0; i < MI; i++) {
            const int row = wm + i * 16 + lo;
            af[i] = *(const bf16x8*)(AsB + cur * TM * 32 + row * 32 +
                                     ((qd ^ ((row >> 1) & 3)) << 3));
        }
#pragma unroll
        for (int j = 0; j < NJ; j++) {
            const int row = wn + j * 16 + lo;
            bfr[j] = *(const bf16x8*)(BsB + cur * TN * 32 + row * 32 +
                                      ((qd ^ ((row >> 1) & 3)) << 3));
        }
#pragma unroll
        for (int i = 0; i < MI; i++)
#pragma unroll
            for (int j = 0; j < NJ; j++)
                acc[i][j] = MFMA16(af[i], bfr[j], acc[i][j]);
    }

    if (EPI == 0 && n0 >= 2 * D_) {
        __bf16* vt = (__bf16*)smem;
        __syncthreads();
#pragma unroll
        for (int i = 0; i < MI; i++)
#pragma unroll
            for (int j = 0; j < NJ; j++)
#pragma unroll
                for (int r = 0; r < 4; r++) {
                    const int lrow = wn + j * 16 + lo;
                    const int lcol = wm + i * 16 + qd * 4 + r;
                    vt[lrow * RP + lcol] =
                        (__bf16)(acc[i][j][r] + bias[n0 + lrow]);
                }
        __syncthreads();
        constexpr int TPR = 256 / TN;
        constexpr int SEG = TM / TPR;
        const int row = tid / TPR;
        const int seg = tid % TPR;
        const int gn  = n0 + row;
        const int bhv = ((m0 >> 11) << 4) + ((gn >> 6) & 15);
        const int dd  = gn & 63;
        __bf16* dst = Vt + ((size_t)bhv * DH_ + dd) * T_ + (m0 & (T_ - 1)) + seg * SEG;
        const __bf16* src = vt + row * RP + seg * SEG;
#pragma unroll
        for (int kk = 0; kk < SEG / 8; kk++)
            *(uint4*)(dst + kk * 8) = *(const uint4*)(src + kk * 8);
        return;
    }

#pragma unroll
    for (int i = 0; i < MI; i++) {
#pragma unroll
        for (int j = 0; j < NJ; j++) {
#pragma unroll
            for (int r = 0; r < 4; r++) {
                int gm = m0 + wm + i * 16 + qd * 4 + r;
                int gn = n0 + wn + j * 16 + lo;
                float v = acc[i][j][r] + bias[gn];
                if (EPI == 1) {
                    Cout[(size_t)gm * N + gn] = v;
                } else {
                    int which = gn >> 10;
                    int bh = ((gm >> 11) << 4) + ((gn >> 6) & 15);
                    int dd = gn & 63;
                    int t  = gm & (T_ - 1);
                    if (which == 0)
                        Q[((size_t)bh * T_ + t) * DH_ + dd] = (__bf16)(v * QSCALE);
                    else
                        Kb[((size_t)bh * T_ + t) * DH_ + dd] = (__bf16)v;
                }
            }
        }
    }
}

// ---------------------------- flash attention ------------------------------
// R20 kernel (frozen).  Grid 1024, 4 blocks/CU (32KB LDS), balanced
// quadruple item map, heads XCD-pinned, K/V dbuf + prefetch, XOR-swizzled,
// fixed m=0 softmax, MFMA ones-trick row sums, in-register softmax via
// swapped QK^T + cvt_pk_bf16 + permlane swaps, setprio around MFMA.

__global__ __launch_bounds__(256) void attn_kernel(
    const __bf16* __restrict__ Q,   // [BH][T][64], pre-scaled
    const __bf16* __restrict__ Kb,  // [BH][T][64]
    const __bf16* __restrict__ Vt,  // [BH][64][T]
    __bf16* __restrict__ O) {       // [B][T][H*64]
    __shared__ __bf16 Ks[2][64 * 64];     // [key][d]  2 x 8 KB, swizzled
    __shared__ __bf16 Vs[2][64 * 64];     // [d][key]  2 x 8 KB, swizzled

    const int tid  = threadIdx.x;
    const int wave = tid >> 6;
    const int lane = tid & 63;
    const int lo   = lane & 15;
    const int qd   = lane >> 4;

    const int g0  = wave * 128 + lane;
    const int g1  = g0 + 64;
    const int r0s = g0 >> 3, c0s = (g0 & 7) ^ (r0s & 7);
    const int r1s = g1 >> 3, c1s = (g1 & 7) ^ (r1s & 7);
    const int so0 = wave * 1024;
    const int so1 = wave * 1024 + 512;

    bf16x8 ones;
#pragma unroll
    for (int i = 0; i < 8; i++) ones[i] = (__bf16)1.0f;

    const int k  = blockIdx.x;            // 0..1023
    const int j  = k >> 5;                // 0..31
    const int bh = k & 31;
    int x;
    if (j < 8)       x = 31 - j;
    else if (j < 16) x = j - 8;
    else if (j < 24) x = 39 - j;
    else             x = j - 16;

    const int b    = bh >> 4;
    const int h    = bh & 15;
    const int q0   = x * 64 + wave * 16;

    const __bf16* Qh = Q + (size_t)bh * T_ * DH_;
    const __bf16* Kh = Kb + (size_t)bh * T_ * DH_;
    const __bf16* Vh = Vt + (size_t)bh * DH_ * T_;

    bf16x8 qa0 = *(const bf16x8*)(Qh + (size_t)(q0 + lo) * DH_ + qd * 8);
    bf16x8 qa1 = *(const bf16x8*)(Qh + (size_t)(q0 + lo) * DH_ + 32 + qd * 8);

    f32x4 oacc[4] = {};
    float lrow[4] = {0.0f, 0.0f, 0.0f, 0.0f};
    const int qrow  = q0 + qd * 4;
    const int ntile = x + 1;

    GLOAD16(Kh + (size_t)r0s * DH_ + c0s * 8, Ks[0] + so0);
    GLOAD16(Kh + (size_t)r1s * DH_ + c1s * 8, Ks[0] + so1);
    GLOAD16(Vh + (size_t)r0s * T_ + c0s * 8, Vs[0] + so0);
    GLOAD16(Vh + (size_t)r1s * T_ + c1s * 8, Vs[0] + so1);
    DRAIN_ALL();
    __syncthreads();

    for (int t = 0; t < ntile; t++) {
        const int j0  = t << 6;
        const int cur = t & 1;
        if (t + 1 < ntile) {
            const int j0n = j0 + 64;
            GLOAD16(Kh + (size_t)(j0n + r0s) * DH_ + c0s * 8, Ks[1 - cur] + so0);
            GLOAD16(Kh + (size_t)(j0n + r1s) * DH_ + c1s * 8, Ks[1 - cur] + so1);
            GLOAD16(Vh + (size_t)r0s * T_ + j0n + c0s * 8, Vs[1 - cur] + so0);
            GLOAD16(Vh + (size_t)r1s * T_ + j0n + c1s * 8, Vs[1 - cur] + so1);
        }

        // ---- S^T = K @ Q^T: lane (lo,qd) holds S[q=lo][key=16g+4qd+r] ----
        f32x4 s[4] = {};
        __builtin_amdgcn_s_setprio(1);
#pragma unroll
        for (int g = 0; g < 4; g++) {
            const int row = g * 16 + lo;
            const __bf16* kr = Ks[cur] + row * 64;
            bf16x8 kb0 = *(const bf16x8*)(kr + ((qd ^ (row & 7)) << 3));
            bf16x8 kb1 = *(const bf16x8*)(kr + (((4 + qd) ^ (row & 7)) << 3));
            s[g] = MFMA16(kb0, qa0, s[g]);
            s[g] = MFMA16(kb1, qa1, s[g]);
        }
        __builtin_amdgcn_s_setprio(0);

        if (j0 + 63 > q0) {
            const int qg = q0 + lo;
#pragma unroll
            for (int g = 0; g < 4; g++) {
                const int kbase = j0 + g * 16 + qd * 4;
#pragma unroll
                for (int r = 0; r < 4; r++)
                    s[g][r] = (kbase + r <= qg) ? s[g][r] : -1e30f;
            }
        }

        // ---- P = exp2(S), packed to bf16 pairs in-register ----
        unsigned Aw[4], Bw[4];
#pragma unroll
        for (int g = 0; g < 4; g++) {
            float p0 = __builtin_amdgcn_exp2f(s[g][0]);
            float p1 = __builtin_amdgcn_exp2f(s[g][1]);
            float p2 = __builtin_amdgcn_exp2f(s[g][2]);
            float p3 = __builtin_amdgcn_exp2f(s[g][3]);
            __asm__("v_cvt_pk_bf16_f32 %0, %1, %2" : "=v"(Aw[g]) : "v"(p0), "v"(p1));
            __asm__("v_cvt_pk_bf16_f32 %0, %1, %2" : "=v"(Bw[g]) : "v"(p2), "v"(p3));
        }
        xpose_pair(Aw[0], Aw[1]);
        xpose_pair(Bw[0], Bw[1]);
        xpose_pair(Aw[2], Aw[3]);
        xpose_pair(Bw[2], Bw[3]);
        u32x4 P0 = {Aw[0], Bw[0], Aw[1], Bw[1]};   // keys  0..31
        u32x4 P1 = {Aw[2], Bw[2], Aw[3], Bw[3]};   // keys 32..63
        bf16x8 pa0 = __builtin_bit_cast(bf16x8, P0);
        bf16x8 pa1 = __builtin_bit_cast(bf16x8, P1);

        // ---- row sums via MFMA ones-trick + O += P @ V ----
        f32x4 ps = {};
        __builtin_amdgcn_s_setprio(1);
        ps = MFMA16(pa0, ones, ps);
        ps = MFMA16(pa1, ones, ps);
#pragma unroll
        for (int c = 0; c < 4; c++) {
            const int row = c * 16 + lo;
            const __bf16* vr = Vs[cur] + row * 64;
            bf16x8 vb0 = *(const bf16x8*)(vr + ((qd ^ (row & 7)) << 3));
            bf16x8 vb1 = *(const bf16x8*)(vr + (((4 + qd) ^ (row & 7)) << 3));
            oacc[c] = MFMA16(pa0, vb0, oacc[c]);
            oacc[c] = MFMA16(pa1, vb1, oacc[c]);
        }
        __builtin_amdgcn_s_setprio(0);
#pragma unroll
        for (int r = 0; r < 4; r++) lrow[r] += ps[r];

        DRAIN_ALL();
        __syncthreads();
    }

    float inv[4];
#pragma unroll
    for (int r = 0; r < 4; r++) inv[r] = 1.0f / lrow[r];
#pragma unroll
    for (int c = 0; c < 4; c++) {
#pragma unroll
        for (int r = 0; r < 4; r++) {
            float val = oacc[c][r] * inv[r];
            size_t idx = ((size_t)b * T_ + (qrow + r)) * D_ + h * DH_ + c * 16 + lo;
            O[idx] = (__bf16)val;
        }
    }
}

// -------------------------------- launcher ---------------------------------

extern "C" void kernel_launch(void* const* d_in, const int* in_sizes, int n_in,
                              void* d_out, int out_size, void* d_ws, size_t ws_size,
                              hipStream_t stream) {
    const float* x      = (const float*)d_in[0];
    const float* w_attn = (const float*)d_in[1];
    const float* b_attn = (const float*)d_in[2];
    const float* w_proj = (const float*)d_in[3];
    const float* b_proj = (const float*)d_in[4];
    float* out = (float*)d_out;

    const size_t MB = (size_t)1 << 20;
    if (ws_size < 48 * MB) return;   // need 48 MB scratch

    char* ws = (char*)d_ws;
    __bf16* xb     = (__bf16*)(ws);              //  8 MB  [M][D]
    __bf16* wattnT = (__bf16*)(ws + 8 * MB);     //  6 MB  [3D][D]
    __bf16* wprojT = (__bf16*)(ws + 14 * MB);    //  2 MB  [D][D]
    __bf16* Qb     = (__bf16*)(ws + 16 * MB);    //  8 MB  [BH][T][64]
    __bf16* Kb     = (__bf16*)(ws + 24 * MB);    //  8 MB  [BH][T][64]
    __bf16* Vt     = (__bf16*)(ws + 32 * MB);    //  8 MB  [BH][64][T]
    __bf16* Ob     = (__bf16*)(ws + 40 * MB);    //  8 MB  [M][D]

    // 1. fused prep: x convert + both weight transposes
    prep_kernel<<<dim3(8192), 256, 0, stream>>>(x, xb, w_attn, wattnT,
                                                w_proj, wprojT);
    // 2. QKV GEMM -> Q(scaled)/K/Vt  (256x256 tiles, fine 4-phase pipeline)
    qkv_gemm256_kernel<<<dim3(12, 16), 512, 0, stream>>>(
        xb, wattnT, b_attn, Qb, Kb, Vt);
    // 3. causal flash attention (1024 blocks, 4/CU, in-register softmax)
    attn_kernel<<<dim3(1024), 256, 0, stream>>>(Qb, Kb, Vt, Ob);
    // 4. output projection (fp32 + bias), 128x64 tiles -> 512 blocks
    gemm_bt_kernel<1, 128, 64><<<dim3(D_ / 64, M_ / 128), 256, 0, stream>>>(
        Ob, wprojT, b_proj, out, nullptr, nullptr, nullptr, M_, D_, D_);
}

// Round 4
// 169.875 us; speedup vs baseline: 1.0604x; 1.0110x over previous
//
#include <hip/hip_runtime.h>

// ---------------------------------------------------------------------------
// FlashAttention block: out = proj(causal_attn(qkv(x)))
// B=2, T=2048, D=1024, H=16, dhead=64.  All GEMMs + attention in bf16 MFMA
// (16x16x32), fp32 accumulate.  fp32 output.
// R23 = R22 with QKV retiled 256x256 -> 256x192 so the grid is 16x16 = 256
// blocks = exactly 1/CU (R21/R22's 192-block grid idled 25% of the chip;
// R22's schedule-only change was exactly neutral -> capacity-bound).
//   - asymmetric B staging: 12KB/slice = 12 wave-chunks; waves 0-5 issue 2
//     B-loads, waves 6-7 none.  vmcnt ledger re-derived per wave class:
//     waves<6 WAIT(6)/WAIT(6) (last tile 4/0), waves>=6 WAIT(4)/WAIT(4)
//     (last tile 2/0).  Wave-uniform branches; one s_barrier per wait point.
//   - element-wise epilogue handles Q/K/V boundary straddle (n0 multiple of
//     192): gn>=2048 -> vt transpose tile [192][264] (101KB), else Q/K
//     scatter.  Same proven store formulas.
//   - 4-phase interleave, XOR swizzle, setprio, XCD swizzle all preserved.
// attn: R20 kernel (in-register softmax via swapped QK^T + cvt_pk +
// permlane swaps, 32KB LDS, setprio).  proj GEMM + prep unchanged.
// ---------------------------------------------------------------------------

#define B_   2
#define T_   2048
#define D_   1024
#define H_   16
#define DH_  64
#define M_   (B_ * T_)       // 4096
#define N1_  (3 * D_)        // 3072
// qscale folds 1/sqrt(dhead) and log2(e) so softmax uses native exp2
#define QSCALE (0.125f * 1.44269504088896340736f)

typedef __bf16 bf16x8 __attribute__((ext_vector_type(8)));
typedef __bf16 bf16x4 __attribute__((ext_vector_type(4)));
typedef float  f32x4  __attribute__((ext_vector_type(4)));
typedef int    i32x2  __attribute__((ext_vector_type(2)));
typedef unsigned u32x4 __attribute__((ext_vector_type(4)));

#define MFMA16(a, b, c) __builtin_amdgcn_mfma_f32_16x16x32_bf16((a), (b), (c), 0, 0, 0)

// async global->LDS, 16B per lane; LDS dest = base + lane*16 (wave-uniform base)
#define GLOAD16(gp, lp)                                                        \
    __builtin_amdgcn_global_load_lds(                                          \
        (const __attribute__((address_space(1))) void*)(gp),                   \
        (__attribute__((address_space(3))) void*)(lp), 16, 0, 0)

#define DRAIN_ALL() __asm__ volatile("s_waitcnt vmcnt(0) lgkmcnt(0)" ::: "memory")

// drain own VMEM to N, drain all DS, then barrier (single asm so the drain
// provably precedes the barrier regardless of scheduling)
#define WAIT_BAR(N)                                                            \
    __asm__ volatile("s_waitcnt vmcnt(" #N ") lgkmcnt(0)\n\ts_barrier" ::: "memory")

#define LGKM0() __asm__ volatile("s_waitcnt lgkmcnt(0)" ::: "memory")
#define BAR()   __asm__ volatile("s_barrier" ::: "memory")

#if defined(__has_builtin)
#if __has_builtin(__builtin_amdgcn_permlane32_swap) && \
    __has_builtin(__builtin_amdgcn_permlane16_swap)
#define HAVE_PERMLANE_SWAP 1
#endif
#endif

// Transpose step for the in-register P-fragment rebuild (see attn_kernel).
__device__ __forceinline__ void xpose_pair(unsigned& a, unsigned& b) {
#if defined(HAVE_PERMLANE_SWAP)
    i32x2 r1 = __builtin_amdgcn_permlane32_swap((int)a, (int)b, false, false);
    i32x2 r2 = __builtin_amdgcn_permlane16_swap(r1[0], r1[1], false, false);
    a = (unsigned)r2[0];
    b = (unsigned)r2[1];
#else
    const int lane = threadIdx.x & 63;
    const int lo   = lane & 15;
    const int srcE = lo + 32 * ((lane >> 4) & 1);
    const int srcO = srcE + 16;
    int aE = __shfl((int)a, srcE, 64), bE = __shfl((int)b, srcE, 64);
    int aO = __shfl((int)a, srcO, 64), bO = __shfl((int)b, srcO, 64);
    unsigned w0 = (lane & 32) ? (unsigned)bE : (unsigned)aE;
    unsigned w2 = (lane & 32) ? (unsigned)bO : (unsigned)aO;
    a = w0;
    b = w2;
#endif
}

// ------------------------------ fused prep ---------------------------------

__global__ __launch_bounds__(256) void prep_kernel(
    const float* __restrict__ x,      __bf16* __restrict__ xb,
    const float* __restrict__ w_attn, __bf16* __restrict__ wattnT,
    const float* __restrict__ w_proj, __bf16* __restrict__ wprojT) {
    __shared__ float tile[32][33];
    int id = blockIdx.x;
    if (id < 4096) {                       // x convert
        int i = (id * 256 + threadIdx.x) * 4;
        float4 f = *(const float4*)(x + i);
        bf16x4 o;
        o[0] = (__bf16)f.x; o[1] = (__bf16)f.y; o[2] = (__bf16)f.z; o[3] = (__bf16)f.w;
        *(bf16x4*)(xb + i) = o;
        return;
    }
    id -= 4096;
    const float* in;
    __bf16* out;
    int C, bx, by;
    if (id < 3072) { in = w_attn; out = wattnT; C = N1_; bx = id % 96; by = id / 96; }
    else { id -= 3072; in = w_proj; out = wprojT; C = D_; bx = id & 31; by = id >> 5; }
    const int tx = threadIdx.x & 31;
    const int ty = threadIdx.x >> 5;       // 0..7
    const int c0 = bx * 32;
    const int r0 = by * 32;
#pragma unroll
    for (int i = 0; i < 4; i++)
        tile[ty + i * 8][tx] = in[(size_t)(r0 + ty + i * 8) * C + c0 + tx];
    __syncthreads();
#pragma unroll
    for (int i = 0; i < 4; i++)
        out[(size_t)(c0 + ty + i * 8) * D_ + r0 + tx] = (__bf16)tile[tx][ty + i * 8];
}

// ----------------------- QKV GEMM, 256x192 pipelined -----------------------
// C[4096][3072] = A[4096][1024] @ Bt[3072][1024]^T + bias, scattered to
// Q (scaled) / K / Vt.  Fine 4-phase schedule per K-tile kt (BK=64):
//   ph1 (ks0,mh0): [issue sA0(kt+1)] WAIT(6|4); read B0(3)+A0h0(4);
//                  lgkm0; prio1; 12 MFMA; prio0; bar
//   ph2 (ks0,mh1): [issue sB0(kt+1), waves 0-5]; read A0h1(4); 12 MFMA; bar
//   ph3 (ks1,mh0): [issue sA1(kt+1)] WAIT(6|4); read B1(3)+A1h0(4); 12 MFMA; bar
//   ph4 (ks1,mh1): [issue sB1(kt+1), waves 0-5]; read A1h1(4); 12 MFMA; bar
// Per-wave issue counts: stageA = 2 loads (all waves); stageB = 2 loads
// (waves 0-5) / 0 (waves 6-7) -> wave-class vmcnt ledger (see WAITs).

__global__ __launch_bounds__(512, 2) void qkv_gemm256_kernel(
    const __bf16* __restrict__ A, const __bf16* __restrict__ Bt,
    const float* __restrict__ bias,
    __bf16* __restrict__ Q, __bf16* __restrict__ Kb, __bf16* __restrict__ Vt) {
    constexpr int BM = 256, BN = 192;
    constexpr int K  = D_;                 // 1024
    constexpr int NK = K / 64;             // 16 K-tiles of 64 (2 ks-slices)
    constexpr int RP = BM + 8;             // vt tile row stride
    constexpr int SMEM_STAGE = 2 * 2 * (BM + BN) * 32 * 2;   // 114688
    constexpr int SMEM_VT    = BN * RP * 2;                  // 101376
    constexpr int SMEM_BYTES = SMEM_VT > SMEM_STAGE ? SMEM_VT : SMEM_STAGE;
    __shared__ __align__(16) char smem[SMEM_BYTES];
    __bf16* As = (__bf16*)smem;            // [2 buf][2 ks][256*32]
    __bf16* Bs = As + 4 * BM * 32;         // [2 buf][2 ks][192*32]

    const int tid  = threadIdx.x;
    const int lane = tid & 63;
    const int wave = tid >> 6;             // 0..7
    const int lo   = lane & 15;
    const int qd   = lane >> 4;
    const int wm   = (wave >> 2) * 128;    // wave M-origin (2 rows of waves)
    const int wn   = (wave & 3) * 48;      // wave N-origin (4 cols of waves)

    // bijective XCD swizzle: 256 blocks, 32 per XCD chunk (2 M-rows x 16 N)
    const int bidl = blockIdx.y * 16 + blockIdx.x;
    const int swz  = (bidl & 7) * 32 + (bidl >> 3);
    const int m0   = (swz >> 4) * BM;
    const int n0   = (swz & 15) * BN;

    // staging decode (proven pattern): chunk g -> LDS byte g*16; row = g>>2,
    // slot = g&3, global k-chunk = slot ^ ((row>>1)&3) = (g&3) ^ ((g>>3)&3)
    const __bf16* gA[2];
#pragma unroll
    for (int c = 0; c < 2; c++) {
        int g  = tid + 512 * c;            // 0..1023 -> rows 0..255
        int cc = (g & 3) ^ ((g >> 3) & 3);
        gA[c] = A + (size_t)(m0 + (g >> 2)) * K + cc * 8;
    }
    // B: 12 wave-chunks of 1KB per ks-slice; waves 0-5 own chunks {2w,2w+1}
    const __bf16* gBn[2];
#pragma unroll
    for (int c = 0; c < 2; c++) {
        int g  = (wave * 2 + c) * 64 + lane;   // 0..767 valid (wave<6)
        int cc = (g & 3) ^ ((g >> 3) & 3);
        int rr = g >> 2;
        rr = rr < BN ? rr : BN - 1;            // clamp (waves 6-7 never issue)
        gBn[c] = Bt + (size_t)(n0 + rr) * K + cc * 8;
    }

    auto stageA = [&](int buf, int ktn, int ks) {
        const int koff = ktn * 64 + ks * 32;
#pragma unroll
        for (int c = 0; c < 2; c++)
            GLOAD16(gA[c] + koff,
                    As + (buf * 2 + ks) * (BM * 32) + (tid + 512 * c) * 8);
    };
    auto stageB = [&](int buf, int ktn, int ks) {
        const int koff = ktn * 64 + ks * 32;
#pragma unroll
        for (int c = 0; c < 2; c++) {
            const int g = (wave * 2 + c) * 64 + lane;
            GLOAD16(gBn[c] + koff,
                    Bs + (buf * 2 + ks) * (BN * 32) + g * 8);
        }
    };

    f32x4 acc[8][3] = {};
    const bool bwave = (wave < 6);

    // prologue: tile 0's stages in consumption order
    stageA(0, 0, 0);
    if (bwave) stageB(0, 0, 0);
    stageA(0, 0, 1);
    if (bwave) stageB(0, 0, 1);

    for (int kt = 0; kt < NK; kt++) {
        const int cur = kt & 1;
        const int nxt = cur ^ 1;
        const bool pf = (kt + 1 < NK);
        const __bf16* A0 = As + cur * 2 * (BM * 32);   // ks0 slice
        const __bf16* A1 = A0 + BM * 32;               // ks1 slice
        const __bf16* B0 = Bs + cur * 2 * (BN * 32);
        const __bf16* B1 = B0 + BN * 32;
        bf16x8 af[4], bfr[3];

        // ---------- phase 1: (ks0, m-half0) ----------
        if (pf) {
            stageA(nxt, kt + 1, 0);
            if (bwave) { WAIT_BAR(6); } else { WAIT_BAR(4); }
        } else {
            if (bwave) { WAIT_BAR(4); } else { WAIT_BAR(2); }
        }
#pragma unroll
        for (int j = 0; j < 3; j++) {
            const int row = wn + j * 16 + lo;
            bfr[j] = *(const bf16x8*)(B0 + row * 32 + ((qd ^ ((row >> 1) & 3)) << 3));
        }
#pragma unroll
        for (int ii = 0; ii < 4; ii++) {
            const int row = wm + ii * 16 + lo;
            af[ii] = *(const bf16x8*)(A0 + row * 32 + ((qd ^ ((row >> 1) & 3)) << 3));
        }
        LGKM0();
        __builtin_amdgcn_s_setprio(1);
#pragma unroll
        for (int ii = 0; ii < 4; ii++)
#pragma unroll
            for (int j = 0; j < 3; j++)
                acc[ii][j] = MFMA16(af[ii], bfr[j], acc[ii][j]);
        __builtin_amdgcn_s_setprio(0);
        BAR();

        // ---------- phase 2: (ks0, m-half1) ----------
        if (pf && bwave) stageB(nxt, kt + 1, 0);
#pragma unroll
        for (int ii = 0; ii < 4; ii++) {
            const int row = wm + 64 + ii * 16 + lo;
            af[ii] = *(const bf16x8*)(A0 + row * 32 + ((qd ^ ((row >> 1) & 3)) << 3));
        }
        LGKM0();
        __builtin_amdgcn_s_setprio(1);
#pragma unroll
        for (int ii = 0; ii < 4; ii++)
#pragma unroll
            for (int j = 0; j < 3; j++)
                acc[4 + ii][j] = MFMA16(af[ii], bfr[j], acc[4 + ii][j]);
        __builtin_amdgcn_s_setprio(0);
        BAR();

        // ---------- phase 3: (ks1, m-half0) ----------
        if (pf) {
            stageA(nxt, kt + 1, 1);
            if (bwave) { WAIT_BAR(6); } else { WAIT_BAR(4); }
        } else {
            WAIT_BAR(0);
        }
#pragma unroll
        for (int j = 0; j < 3; j++) {
            const int row = wn + j * 16 + lo;
            bfr[j] = *(const bf16x8*)(B1 + row * 32 + ((qd ^ ((row >> 1) & 3)) << 3));
        }
#pragma unroll
        for (int ii = 0; ii < 4; ii++) {
            const int row = wm + ii * 16 + lo;
            af[ii] = *(const bf16x8*)(A1 + row * 32 + ((qd ^ ((row >> 1) & 3)) << 3));
        }
        LGKM0();
        __builtin_amdgcn_s_setprio(1);
#pragma unroll
        for (int ii = 0; ii < 4; ii++)
#pragma unroll
            for (int j = 0; j < 3; j++)
                acc[ii][j] = MFMA16(af[ii], bfr[j], acc[ii][j]);
        __builtin_amdgcn_s_setprio(0);
        BAR();

        // ---------- phase 4: (ks1, m-half1) ----------
        if (pf && bwave) stageB(nxt, kt + 1, 1);
#pragma unroll
        for (int ii = 0; ii < 4; ii++) {
            const int row = wm + 64 + ii * 16 + lo;
            af[ii] = *(const bf16x8*)(A1 + row * 32 + ((qd ^ ((row >> 1) & 3)) << 3));
        }
        LGKM0();
        __builtin_amdgcn_s_setprio(1);
#pragma unroll
        for (int ii = 0; ii < 4; ii++)
#pragma unroll
            for (int j = 0; j < 3; j++)
                acc[4 + ii][j] = MFMA16(af[ii], bfr[j], acc[4 + ii][j]);
        __builtin_amdgcn_s_setprio(0);
        BAR();
    }

    // ---- unified epilogue: Q/K scatter + V transpose (handles straddle) ----
    const bool hasV = (n0 + BN > 2 * D_);
    __bf16* vt = (__bf16*)smem;            // [BN][RP]
    __syncthreads();
#pragma unroll
    for (int i = 0; i < 8; i++) {
#pragma unroll
        for (int j = 0; j < 3; j++) {
#pragma unroll
            for (int r = 0; r < 4; r++) {
                const int lrow = wn + j * 16 + lo;        // gn-local
                const int gn   = n0 + lrow;
                const int gm   = m0 + wm + i * 16 + qd * 4 + r;
                float v = acc[i][j][r] + bias[gn];
                if (gn >= 2 * D_) {                       // V: LDS transpose
                    const int lcol = wm + i * 16 + qd * 4 + r;
                    vt[lrow * RP + lcol] = (__bf16)v;
                } else {                                  // Q/K scatter
                    int which = gn >> 10;                 // 0=q 1=k
                    int bh = ((gm >> 11) << 4) + ((gn >> 6) & 15);
                    int dd = gn & 63;
                    int t  = gm & (T_ - 1);
                    if (which == 0)
                        Q[((size_t)bh * T_ + t) * DH_ + dd] = (__bf16)(v * QSCALE);
                    else
                        Kb[((size_t)bh * T_ + t) * DH_ + dd] = (__bf16)v;
                }
            }
        }
    }
    if (hasV) {
        __syncthreads();
        const int row = tid >> 1;          // gn-local row
        const int seg = tid & 1;           // 2 threads/row, 128 elems each
        if (row < BN && n0 + row >= 2 * D_) {
            const int gn  = n0 + row;
            const int bhv = ((m0 >> 11) << 4) + ((gn >> 6) & 15);
            const int dd  = gn & 63;
            __bf16* dst = Vt + ((size_t)bhv * DH_ + dd) * T_ + (m0 & (T_ - 1)) + seg * 128;
            const __bf16* src = vt + row * RP + seg * 128;
#pragma unroll
            for (int kk = 0; kk < 16; kk++)    // 16B stores
                *(uint4*)(dst + kk * 8) = *(const uint4*)(src + kk * 8);
        }
    }
}

// ------------------------------- MFMA GEMM ---------------------------------
// (proj only now)  C[M][N] = A[M][K] @ Bt[N][K]^T + bias.  128x64 tiles,
// 3-deep LDS pipeline, vmcnt(loads-per-tile) waits, raw s_barrier,
// XOR-swizzled staging.  EPI 1: fp32 out + bias.

template <int EPI, int TM, int TN>
__global__ __launch_bounds__(256) void gemm_bt_kernel(
    const __bf16* __restrict__ A, const __bf16* __restrict__ Bt,
    const float* __restrict__ bias, float* __restrict__ Cout,
    __bf16* __restrict__ Q, __bf16* __restrict__ Kb, __bf16* __restrict__ Vt,
    int M, int N, int K) {
    constexpr int MI  = TM / 32;          // m-frags per wave
    constexpr int NJ  = TN / 32;          // n-frags per wave
    constexpr int WM  = MI * 16;          // rows per wave
    constexpr int WN  = NJ * 16;          // cols per wave
    constexpr int ACH = TM / 64;          // A-chunk rounds per thread
    constexpr int BCH = TN / 64;          // B-chunk rounds per thread
    constexpr int RP  = TM + 8;           // vt tile row stride (elems)
    constexpr int SMEM_STAGE = 3 * (TM + TN) * 32 * 2;
    constexpr int SMEM_VT    = (EPI == 0) ? TN * RP * 2 : 0;
    constexpr int SMEM_BYTES = SMEM_STAGE > SMEM_VT ? SMEM_STAGE : SMEM_VT;
    __shared__ __align__(16) char smem[SMEM_BYTES];
    __bf16* AsB = (__bf16*)smem;          // [3][TM*32]
    __bf16* BsB = AsB + 3 * TM * 32;      // [3][TN*32]

    const int tid  = threadIdx.x;
    const int lane = tid & 63;
    const int wave = tid >> 6;
    const int lo   = lane & 15;
    const int qd   = lane >> 4;
    const int wm   = (wave >> 1) * WM;
    const int wn   = (wave & 1) * WN;
    const int m0   = blockIdx.y * TM;
    const int n0   = blockIdx.x * TN;

    const __bf16* gA[ACH];
    const __bf16* gB[BCH];
#pragma unroll
    for (int c = 0; c < ACH; c++) {
        int g = tid + 256 * c;
        int cc = (g & 3) ^ ((g >> 3) & 3);
        gA[c] = A + (size_t)(m0 + (g >> 2)) * K + cc * 8;
    }
#pragma unroll
    for (int c = 0; c < BCH; c++) {
        int g = tid + 256 * c;
        int cc = (g & 3) ^ ((g >> 3) & 3);
        gB[c] = Bt + (size_t)(n0 + (g >> 2)) * K + cc * 8;
    }

    f32x4 acc[MI][NJ] = {};
    const int nk = K >> 5;

    // prologue: stage tiles 0 and 1 (2-deep)
#pragma unroll
    for (int pb = 0; pb < 2; pb++) {
        const int k0 = pb << 5;
#pragma unroll
        for (int c = 0; c < ACH; c++)
            GLOAD16(gA[c] + k0, AsB + pb * TM * 32 + (tid + 256 * c) * 8);
#pragma unroll
        for (int c = 0; c < BCH; c++)
            GLOAD16(gB[c] + k0, BsB + pb * TN * 32 + (tid + 256 * c) * 8);
    }

    for (int kt = 0; kt < nk; kt++) {
        const int cur = kt % 3;
        if (kt + 1 < nk) {
            __asm__ volatile("s_waitcnt vmcnt(%0) lgkmcnt(0)" ::
                             "i"(ACH + BCH) : "memory");
        } else {
            __asm__ volatile("s_waitcnt vmcnt(0) lgkmcnt(0)" ::: "memory");
        }
        __asm__ volatile("s_barrier" ::: "memory");
        if (kt + 2 < nk) {
            const int k0n = (kt + 2) << 5;
            const int nb  = (kt + 2) % 3;
#pragma unroll
            for (int c = 0; c < ACH; c++)
                GLOAD16(gA[c] + k0n, AsB + nb * TM * 32 + (tid + 256 * c) * 8);
#pragma unroll
            for (int c = 0; c < BCH; c++)
                GLOAD16(gB[c] + k0n, BsB + nb * TN * 32 + (tid + 256 * c) * 8);
        }
        bf16x8 af[MI], bfr[NJ];
#pragma unroll
        for (int i = 0; i < MI; i++) {
            const int row = wm + i * 16 + lo;
            af[i] = *(const bf16x8*)(AsB + cur * TM * 32 + row * 32 +
                                     ((qd ^ ((row >> 1) & 3)) << 3));
        }
#pragma unroll
        for (int j = 0; j < NJ; j++) {
            const int row = wn + j * 16 + lo;
            bfr[j] = *(const bf16x8*)(BsB + cur * TN * 32 + row * 32 +
                                      ((qd ^ ((row >> 1) & 3)) << 3));
        }
#pragma unroll
        for (int i = 0; i < MI; i++)
#pragma unroll
            for (int j = 0; j < NJ; j++)
                acc[i][j] = MFMA16(af[i], bfr[j], acc[i][j]);
    }

    if (EPI == 0 && n0 >= 2 * D_) {
        __bf16* vt = (__bf16*)smem;
        __syncthreads();
#pragma unroll
        for (int i = 0; i < MI; i++)
#pragma unroll
            for (int j = 0; j < NJ; j++)
#pragma unroll
                for (int r = 0; r < 4; r++) {
                    const int lrow = wn + j * 16 + lo;
                    const int lcol = wm + i * 16 + qd * 4 + r;
                    vt[lrow * RP + lcol] =
                        (__bf16)(acc[i][j][r] + bias[n0 + lrow]);
                }
        __syncthreads();
        constexpr int TPR = 256 / TN;
        constexpr int SEG = TM / TPR;
        const int row = tid / TPR;
        const int seg = tid % TPR;
        const int gn  = n0 + row;
        const int bhv = ((m0 >> 11) << 4) + ((gn >> 6) & 15);
        const int dd  = gn & 63;
        __bf16* dst = Vt + ((size_t)bhv * DH_ + dd) * T_ + (m0 & (T_ - 1)) + seg * SEG;
        const __bf16* src = vt + row * RP + seg * SEG;
#pragma unroll
        for (int kk = 0; kk < SEG / 8; kk++)
            *(uint4*)(dst + kk * 8) = *(const uint4*)(src + kk * 8);
        return;
    }

#pragma unroll
    for (int i = 0; i < MI; i++) {
#pragma unroll
        for (int j = 0; j < NJ; j++) {
#pragma unroll
            for (int r = 0; r < 4; r++) {
                int gm = m0 + wm + i * 16 + qd * 4 + r;
                int gn = n0 + wn + j * 16 + lo;
                float v = acc[i][j][r] + bias[gn];
                if (EPI == 1) {
                    Cout[(size_t)gm * N + gn] = v;
                } else {
                    int which = gn >> 10;
                    int bh = ((gm >> 11) << 4) + ((gn >> 6) & 15);
                    int dd = gn & 63;
                    int t  = gm & (T_ - 1);
                    if (which == 0)
                        Q[((size_t)bh * T_ + t) * DH_ + dd] = (__bf16)(v * QSCALE);
                    else
                        Kb[((size_t)bh * T_ + t) * DH_ + dd] = (__bf16)v;
                }
            }
        }
    }
}

// ---------------------------- flash attention ------------------------------
// R20 kernel (frozen).  Grid 1024, 4 blocks/CU (32KB LDS), balanced
// quadruple item map, heads XCD-pinned, K/V dbuf + prefetch, XOR-swizzled,
// fixed m=0 softmax, MFMA ones-trick row sums, in-register softmax via
// swapped QK^T + cvt_pk_bf16 + permlane swaps, setprio around MFMA.

__global__ __launch_bounds__(256) void attn_kernel(
    const __bf16* __restrict__ Q,   // [BH][T][64], pre-scaled
    const __bf16* __restrict__ Kb,  // [BH][T][64]
    const __bf16* __restrict__ Vt,  // [BH][64][T]
    __bf16* __restrict__ O) {       // [B][T][H*64]
    __shared__ __bf16 Ks[2][64 * 64];     // [key][d]  2 x 8 KB, swizzled
    __shared__ __bf16 Vs[2][64 * 64];     // [d][key]  2 x 8 KB, swizzled

    const int tid  = threadIdx.x;
    const int wave = tid >> 6;
    const int lane = tid & 63;
    const int lo   = lane & 15;
    const int qd   = lane >> 4;

    const int g0  = wave * 128 + lane;
    const int g1  = g0 + 64;
    const int r0s = g0 >> 3, c0s = (g0 & 7) ^ (r0s & 7);
    const int r1s = g1 >> 3, c1s = (g1 & 7) ^ (r1s & 7);
    const int so0 = wave * 1024;
    const int so1 = wave * 1024 + 512;

    bf16x8 ones;
#pragma unroll
    for (int i = 0; i < 8; i++) ones[i] = (__bf16)1.0f;

    const int k  = blockIdx.x;            // 0..1023
    const int j  = k >> 5;                // 0..31
    const int bh = k & 31;
    int x;
    if (j < 8)       x = 31 - j;
    else if (j < 16) x = j - 8;
    else if (j < 24) x = 39 - j;
    else             x = j - 16;

    const int b    = bh >> 4;
    const int h    = bh & 15;
    const int q0   = x * 64 + wave * 16;

    const __bf16* Qh = Q + (size_t)bh * T_ * DH_;
    const __bf16* Kh = Kb + (size_t)bh * T_ * DH_;
    const __bf16* Vh = Vt + (size_t)bh * DH_ * T_;

    bf16x8 qa0 = *(const bf16x8*)(Qh + (size_t)(q0 + lo) * DH_ + qd * 8);
    bf16x8 qa1 = *(const bf16x8*)(Qh + (size_t)(q0 + lo) * DH_ + 32 + qd * 8);

    f32x4 oacc[4] = {};
    float lrow[4] = {0.0f, 0.0f, 0.0f, 0.0f};
    const int qrow  = q0 + qd * 4;
    const int ntile = x + 1;

    GLOAD16(Kh + (size_t)r0s * DH_ + c0s * 8, Ks[0] + so0);
    GLOAD16(Kh + (size_t)r1s * DH_ + c1s * 8, Ks[0] + so1);
    GLOAD16(Vh + (size_t)r0s * T_ + c0s * 8, Vs[0] + so0);
    GLOAD16(Vh + (size_t)r1s * T_ + c1s * 8, Vs[0] + so1);
    DRAIN_ALL();
    __syncthreads();

    for (int t = 0; t < ntile; t++) {
        const int j0  = t << 6;
        const int cur = t & 1;
        if (t + 1 < ntile) {
            const int j0n = j0 + 64;
            GLOAD16(Kh + (size_t)(j0n + r0s) * DH_ + c0s * 8, Ks[1 - cur] + so0);
            GLOAD16(Kh + (size_t)(j0n + r1s) * DH_ + c1s * 8, Ks[1 - cur] + so1);
            GLOAD16(Vh + (size_t)r0s * T_ + j0n + c0s * 8, Vs[1 - cur] + so0);
            GLOAD16(Vh + (size_t)r1s * T_ + j0n + c1s * 8, Vs[1 - cur] + so1);
        }

        // ---- S^T = K @ Q^T: lane (lo,qd) holds S[q=lo][key=16g+4qd+r] ----
        f32x4 s[4] = {};
        __builtin_amdgcn_s_setprio(1);
#pragma unroll
        for (int g = 0; g < 4; g++) {
            const int row = g * 16 + lo;
            const __bf16* kr = Ks[cur] + row * 64;
            bf16x8 kb0 = *(const bf16x8*)(kr + ((qd ^ (row & 7)) << 3));
            bf16x8 kb1 = *(const bf16x8*)(kr + (((4 + qd) ^ (row & 7)) << 3));
            s[g] = MFMA16(kb0, qa0, s[g]);
            s[g] = MFMA16(kb1, qa1, s[g]);
        }
        __builtin_amdgcn_s_setprio(0);

        if (j0 + 63 > q0) {
            const int qg = q0 + lo;
#pragma unroll
            for (int g = 0; g < 4; g++) {
                const int kbase = j0 + g * 16 + qd * 4;
#pragma unroll
                for (int r = 0; r < 4; r++)
                    s[g][r] = (kbase + r <= qg) ? s[g][r] : -1e30f;
            }
        }

        // ---- P = exp2(S), packed to bf16 pairs in-register ----
        unsigned Aw[4], Bw[4];
#pragma unroll
        for (int g = 0; g < 4; g++) {
            float p0 = __builtin_amdgcn_exp2f(s[g][0]);
            float p1 = __builtin_amdgcn_exp2f(s[g][1]);
            float p2 = __builtin_amdgcn_exp2f(s[g][2]);
            float p3 = __builtin_amdgcn_exp2f(s[g][3]);
            __asm__("v_cvt_pk_bf16_f32 %0, %1, %2" : "=v"(Aw[g]) : "v"(p0), "v"(p1));
            __asm__("v_cvt_pk_bf16_f32 %0, %1, %2" : "=v"(Bw[g]) : "v"(p2), "v"(p3));
        }
        xpose_pair(Aw[0], Aw[1]);
        xpose_pair(Bw[0], Bw[1]);
        xpose_pair(Aw[2], Aw[3]);
        xpose_pair(Bw[2], Bw[3]);
        u32x4 P0 = {Aw[0], Bw[0], Aw[1], Bw[1]};   // keys  0..31
        u32x4 P1 = {Aw[2], Bw[2], Aw[3], Bw[3]};   // keys 32..63
        bf16x8 pa0 = __builtin_bit_cast(bf16x8, P0);
        bf16x8 pa1 = __builtin_bit_cast(bf16x8, P1);

        // ---- row sums via MFMA ones-trick + O += P @ V ----
        f32x4 ps = {};
        __builtin_amdgcn_s_setprio(1);
        ps = MFMA16(pa0, ones, ps);
        ps = MFMA16(pa1, ones, ps);
#pragma unroll
        for (int c = 0; c < 4; c++) {
            const int row = c * 16 + lo;
            const __bf16* vr = Vs[cur] + row * 64;
            bf16x8 vb0 = *(const bf16x8*)(vr + ((qd ^ (row & 7)) << 3));
            bf16x8 vb1 = *(const bf16x8*)(vr + (((4 + qd) ^ (row & 7)) << 3));
            oacc[c] = MFMA16(pa0, vb0, oacc[c]);
            oacc[c] = MFMA16(pa1, vb1, oacc[c]);
        }
        __builtin_amdgcn_s_setprio(0);
#pragma unroll
        for (int r = 0; r < 4; r++) lrow[r] += ps[r];

        DRAIN_ALL();
        __syncthreads();
    }

    float inv[4];
#pragma unroll
    for (int r = 0; r < 4; r++) inv[r] = 1.0f / lrow[r];
#pragma unroll
    for (int c = 0; c < 4; c++) {
#pragma unroll
        for (int r = 0; r < 4; r++) {
            float val = oacc[c][r] * inv[r];
            size_t idx = ((size_t)b * T_ + (qrow + r)) * D_ + h * DH_ + c * 16 + lo;
            O[idx] = (__bf16)val;
        }
    }
}

// -------------------------------- launcher ---------------------------------

extern "C" void kernel_launch(void* const* d_in, const int* in_sizes, int n_in,
                              void* d_out, int out_size, void* d_ws, size_t ws_size,
                              hipStream_t stream) {
    const float* x      = (const float*)d_in[0];
    const float* w_attn = (const float*)d_in[1];
    const float* b_attn = (const float*)d_in[2];
    const float* w_proj = (const float*)d_in[3];
    const float* b_proj = (const float*)d_in[4];
    float* out = (float*)d_out;

    const size_t MB = (size_t)1 << 20;
    if (ws_size < 48 * MB) return;   // need 48 MB scratch

    char* ws = (char*)d_ws;
    __bf16* xb     = (__bf16*)(ws);              //  8 MB  [M][D]
    __bf16* wattnT = (__bf16*)(ws + 8 * MB);     //  6 MB  [3D][D]
    __bf16* wprojT = (__bf16*)(ws + 14 * MB);    //  2 MB  [D][D]
    __bf16* Qb     = (__bf16*)(ws + 16 * MB);    //  8 MB  [BH][T][64]
    __bf16* Kb     = (__bf16*)(ws + 24 * MB);    //  8 MB  [BH][T][64]
    __bf16* Vt     = (__bf16*)(ws + 32 * MB);    //  8 MB  [BH][64][T]
    __bf16* Ob     = (__bf16*)(ws + 40 * MB);    //  8 MB  [M][D]

    // 1. fused prep: x convert + both weight transposes
    prep_kernel<<<dim3(8192), 256, 0, stream>>>(x, xb, w_attn, wattnT,
                                                w_proj, wprojT);
    // 2. QKV GEMM -> Q(scaled)/K/Vt  (256x192 tiles, 256 blocks = 1/CU)
    qkv_gemm256_kernel<<<dim3(16, 16), 512, 0, stream>>>(
        xb, wattnT, b_attn, Qb, Kb, Vt);
    // 3. causal flash attention (1024 blocks, 4/CU, in-register softmax)
    attn_kernel<<<dim3(1024), 256, 0, stream>>>(Qb, Kb, Vt, Ob);
    // 4. output projection (fp32 + bias), 128x64 tiles -> 512 blocks
    gemm_bt_kernel<1, 128, 64><<<dim3(D_ / 64, M_ / 128), 256, 0, stream>>>(
        Ob, wprojT, b_proj, out, nullptr, nullptr, nullptr, M_, D_, D_);
}

// Round 5
// 161.530 us; speedup vs baseline: 1.1152x; 1.0517x over previous
//
#include <hip/hip_runtime.h>

// ---------------------------------------------------------------------------
// FlashAttention block: out = proj(causal_attn(qkv(x)))
// B=2, T=2048, D=1024, H=16, dhead=64.  All GEMMs + attention in bf16 MFMA
// (16x16x32), fp32 accumulate.  fp32 output.
// R24 = R23 + attention restructured to halve LDS read volume (the measured
// invariant: attn stuck at 46.2us across softmax/occupancy changes; per-CU
// LDS port demand ~3x MFMA demand -> LDS-throughput-bound):
//   - wave w = (qh=w>>1, kh=w&1): each wave computes PARTIAL O(32q x 64d)
//     over its 32-key half of every tile.  K reads 4 (was 8), V reads 4
//     (was 8) per wave-tile; MFMA count unchanged (8 QK + 2 ones + 8 PV);
//     no duplicated work anywhere.
//   - end-of-kernel combine: kh=1 wave writes oacc+lrow partials into the
//     (free) K/V LDS, kh=0 wave adds, normalizes, stores O.  Once per block.
//   - __launch_bounds__(256,4) pins VGPR<=128 so 4 blocks/CU hold.
//   - in-register softmax (swapped QK^T + cvt_pk + permlane), XOR-swizzled
//     staging, balanced item map, XCD-pinned heads all preserved.
// proj GEMM retiled 128x64 -> 128x128 (R0's proven config): grid 8x32=256
// blocks = exactly 1/CU, 2x MFMA per LDS read.  QKV + prep frozen from R23.
// ---------------------------------------------------------------------------

#define B_   2
#define T_   2048
#define D_   1024
#define H_   16
#define DH_  64
#define M_   (B_ * T_)       // 4096
#define N1_  (3 * D_)        // 3072
// qscale folds 1/sqrt(dhead) and log2(e) so softmax uses native exp2
#define QSCALE (0.125f * 1.44269504088896340736f)

typedef __bf16 bf16x8 __attribute__((ext_vector_type(8)));
typedef __bf16 bf16x4 __attribute__((ext_vector_type(4)));
typedef float  f32x4  __attribute__((ext_vector_type(4)));
typedef int    i32x2  __attribute__((ext_vector_type(2)));
typedef unsigned u32x4 __attribute__((ext_vector_type(4)));

#define MFMA16(a, b, c) __builtin_amdgcn_mfma_f32_16x16x32_bf16((a), (b), (c), 0, 0, 0)

// async global->LDS, 16B per lane; LDS dest = base + lane*16 (wave-uniform base)
#define GLOAD16(gp, lp)                                                        \
    __builtin_amdgcn_global_load_lds(                                          \
        (const __attribute__((address_space(1))) void*)(gp),                   \
        (__attribute__((address_space(3))) void*)(lp), 16, 0, 0)

#define DRAIN_ALL() __asm__ volatile("s_waitcnt vmcnt(0) lgkmcnt(0)" ::: "memory")

// drain own VMEM to N, drain all DS, then barrier (single asm so the drain
// provably precedes the barrier regardless of scheduling)
#define WAIT_BAR(N)                                                            \
    __asm__ volatile("s_waitcnt vmcnt(" #N ") lgkmcnt(0)\n\ts_barrier" ::: "memory")

#define LGKM0() __asm__ volatile("s_waitcnt lgkmcnt(0)" ::: "memory")
#define BAR()   __asm__ volatile("s_barrier" ::: "memory")

#if defined(__has_builtin)
#if __has_builtin(__builtin_amdgcn_permlane32_swap) && \
    __has_builtin(__builtin_amdgcn_permlane16_swap)
#define HAVE_PERMLANE_SWAP 1
#endif
#endif

// Transpose step for the in-register P-fragment rebuild (see attn_kernel).
__device__ __forceinline__ void xpose_pair(unsigned& a, unsigned& b) {
#if defined(HAVE_PERMLANE_SWAP)
    i32x2 r1 = __builtin_amdgcn_permlane32_swap((int)a, (int)b, false, false);
    i32x2 r2 = __builtin_amdgcn_permlane16_swap(r1[0], r1[1], false, false);
    a = (unsigned)r2[0];
    b = (unsigned)r2[1];
#else
    const int lane = threadIdx.x & 63;
    const int lo   = lane & 15;
    const int srcE = lo + 32 * ((lane >> 4) & 1);
    const int srcO = srcE + 16;
    int aE = __shfl((int)a, srcE, 64), bE = __shfl((int)b, srcE, 64);
    int aO = __shfl((int)a, srcO, 64), bO = __shfl((int)b, srcO, 64);
    unsigned w0 = (lane & 32) ? (unsigned)bE : (unsigned)aE;
    unsigned w2 = (lane & 32) ? (unsigned)bO : (unsigned)aO;
    a = w0;
    b = w2;
#endif
}

// ------------------------------ fused prep ---------------------------------

__global__ __launch_bounds__(256) void prep_kernel(
    const float* __restrict__ x,      __bf16* __restrict__ xb,
    const float* __restrict__ w_attn, __bf16* __restrict__ wattnT,
    const float* __restrict__ w_proj, __bf16* __restrict__ wprojT) {
    __shared__ float tile[32][33];
    int id = blockIdx.x;
    if (id < 4096) {                       // x convert
        int i = (id * 256 + threadIdx.x) * 4;
        float4 f = *(const float4*)(x + i);
        bf16x4 o;
        o[0] = (__bf16)f.x; o[1] = (__bf16)f.y; o[2] = (__bf16)f.z; o[3] = (__bf16)f.w;
        *(bf16x4*)(xb + i) = o;
        return;
    }
    id -= 4096;
    const float* in;
    __bf16* out;
    int C, bx, by;
    if (id < 3072) { in = w_attn; out = wattnT; C = N1_; bx = id % 96; by = id / 96; }
    else { id -= 3072; in = w_proj; out = wprojT; C = D_; bx = id & 31; by = id >> 5; }
    const int tx = threadIdx.x & 31;
    const int ty = threadIdx.x >> 5;       // 0..7
    const int c0 = bx * 32;
    const int r0 = by * 32;
#pragma unroll
    for (int i = 0; i < 4; i++)
        tile[ty + i * 8][tx] = in[(size_t)(r0 + ty + i * 8) * C + c0 + tx];
    __syncthreads();
#pragma unroll
    for (int i = 0; i < 4; i++)
        out[(size_t)(c0 + ty + i * 8) * D_ + r0 + tx] = (__bf16)tile[tx][ty + i * 8];
}

// ----------------------- QKV GEMM, 256x192 pipelined -----------------------
// Frozen from R23.  Fine 4-phase schedule per K-tile (BK=64), asymmetric B
// staging (waves 0-5), wave-class vmcnt ledger, unified straddle epilogue.

__global__ __launch_bounds__(512, 2) void qkv_gemm256_kernel(
    const __bf16* __restrict__ A, const __bf16* __restrict__ Bt,
    const float* __restrict__ bias,
    __bf16* __restrict__ Q, __bf16* __restrict__ Kb, __bf16* __restrict__ Vt) {
    constexpr int BM = 256, BN = 192;
    constexpr int K  = D_;                 // 1024
    constexpr int NK = K / 64;             // 16 K-tiles of 64 (2 ks-slices)
    constexpr int RP = BM + 8;             // vt tile row stride
    constexpr int SMEM_STAGE = 2 * 2 * (BM + BN) * 32 * 2;   // 114688
    constexpr int SMEM_VT    = BN * RP * 2;                  // 101376
    constexpr int SMEM_BYTES = SMEM_VT > SMEM_STAGE ? SMEM_VT : SMEM_STAGE;
    __shared__ __align__(16) char smem[SMEM_BYTES];
    __bf16* As = (__bf16*)smem;            // [2 buf][2 ks][256*32]
    __bf16* Bs = As + 4 * BM * 32;         // [2 buf][2 ks][192*32]

    const int tid  = threadIdx.x;
    const int lane = tid & 63;
    const int wave = tid >> 6;             // 0..7
    const int lo   = lane & 15;
    const int qd   = lane >> 4;
    const int wm   = (wave >> 2) * 128;    // wave M-origin (2 rows of waves)
    const int wn   = (wave & 3) * 48;      // wave N-origin (4 cols of waves)

    // bijective XCD swizzle: 256 blocks, 32 per XCD chunk (2 M-rows x 16 N)
    const int bidl = blockIdx.y * 16 + blockIdx.x;
    const int swz  = (bidl & 7) * 32 + (bidl >> 3);
    const int m0   = (swz >> 4) * BM;
    const int n0   = (swz & 15) * BN;

    // staging decode (proven pattern): chunk g -> LDS byte g*16; row = g>>2,
    // slot = g&3, global k-chunk = slot ^ ((row>>1)&3) = (g&3) ^ ((g>>3)&3)
    const __bf16* gA[2];
#pragma unroll
    for (int c = 0; c < 2; c++) {
        int g  = tid + 512 * c;            // 0..1023 -> rows 0..255
        int cc = (g & 3) ^ ((g >> 3) & 3);
        gA[c] = A + (size_t)(m0 + (g >> 2)) * K + cc * 8;
    }
    // B: 12 wave-chunks of 1KB per ks-slice; waves 0-5 own chunks {2w,2w+1}
    const __bf16* gBn[2];
#pragma unroll
    for (int c = 0; c < 2; c++) {
        int g  = (wave * 2 + c) * 64 + lane;   // 0..767 valid (wave<6)
        int cc = (g & 3) ^ ((g >> 3) & 3);
        int rr = g >> 2;
        rr = rr < BN ? rr : BN - 1;            // clamp (waves 6-7 never issue)
        gBn[c] = Bt + (size_t)(n0 + rr) * K + cc * 8;
    }

    auto stageA = [&](int buf, int ktn, int ks) {
        const int koff = ktn * 64 + ks * 32;
#pragma unroll
        for (int c = 0; c < 2; c++)
            GLOAD16(gA[c] + koff,
                    As + (buf * 2 + ks) * (BM * 32) + (tid + 512 * c) * 8);
    };
    auto stageB = [&](int buf, int ktn, int ks) {
        const int koff = ktn * 64 + ks * 32;
#pragma unroll
        for (int c = 0; c < 2; c++) {
            const int g = (wave * 2 + c) * 64 + lane;
            GLOAD16(gBn[c] + koff,
                    Bs + (buf * 2 + ks) * (BN * 32) + g * 8);
        }
    };

    f32x4 acc[8][3] = {};
    const bool bwave = (wave < 6);

    // prologue: tile 0's stages in consumption order
    stageA(0, 0, 0);
    if (bwave) stageB(0, 0, 0);
    stageA(0, 0, 1);
    if (bwave) stageB(0, 0, 1);

    for (int kt = 0; kt < NK; kt++) {
        const int cur = kt & 1;
        const int nxt = cur ^ 1;
        const bool pf = (kt + 1 < NK);
        const __bf16* A0 = As + cur * 2 * (BM * 32);   // ks0 slice
        const __bf16* A1 = A0 + BM * 32;               // ks1 slice
        const __bf16* B0 = Bs + cur * 2 * (BN * 32);
        const __bf16* B1 = B0 + BN * 32;
        bf16x8 af[4], bfr[3];

        // ---------- phase 1: (ks0, m-half0) ----------
        if (pf) {
            stageA(nxt, kt + 1, 0);
            if (bwave) { WAIT_BAR(6); } else { WAIT_BAR(4); }
        } else {
            if (bwave) { WAIT_BAR(4); } else { WAIT_BAR(2); }
        }
#pragma unroll
        for (int j = 0; j < 3; j++) {
            const int row = wn + j * 16 + lo;
            bfr[j] = *(const bf16x8*)(B0 + row * 32 + ((qd ^ ((row >> 1) & 3)) << 3));
        }
#pragma unroll
        for (int ii = 0; ii < 4; ii++) {
            const int row = wm + ii * 16 + lo;
            af[ii] = *(const bf16x8*)(A0 + row * 32 + ((qd ^ ((row >> 1) & 3)) << 3));
        }
        LGKM0();
        __builtin_amdgcn_s_setprio(1);
#pragma unroll
        for (int ii = 0; ii < 4; ii++)
#pragma unroll
            for (int j = 0; j < 3; j++)
                acc[ii][j] = MFMA16(af[ii], bfr[j], acc[ii][j]);
        __builtin_amdgcn_s_setprio(0);
        BAR();

        // ---------- phase 2: (ks0, m-half1) ----------
        if (pf && bwave) stageB(nxt, kt + 1, 0);
#pragma unroll
        for (int ii = 0; ii < 4; ii++) {
            const int row = wm + 64 + ii * 16 + lo;
            af[ii] = *(const bf16x8*)(A0 + row * 32 + ((qd ^ ((row >> 1) & 3)) << 3));
        }
        LGKM0();
        __builtin_amdgcn_s_setprio(1);
#pragma unroll
        for (int ii = 0; ii < 4; ii++)
#pragma unroll
            for (int j = 0; j < 3; j++)
                acc[4 + ii][j] = MFMA16(af[ii], bfr[j], acc[4 + ii][j]);
        __builtin_amdgcn_s_setprio(0);
        BAR();

        // ---------- phase 3: (ks1, m-half0) ----------
        if (pf) {
            stageA(nxt, kt + 1, 1);
            if (bwave) { WAIT_BAR(6); } else { WAIT_BAR(4); }
        } else {
            WAIT_BAR(0);
        }
#pragma unroll
        for (int j = 0; j < 3; j++) {
            const int row = wn + j * 16 + lo;
            bfr[j] = *(const bf16x8*)(B1 + row * 32 + ((qd ^ ((row >> 1) & 3)) << 3));
        }
#pragma unroll
        for (int ii = 0; ii < 4; ii++) {
            const int row = wm + ii * 16 + lo;
            af[ii] = *(const bf16x8*)(A1 + row * 32 + ((qd ^ ((row >> 1) & 3)) << 3));
        }
        LGKM0();
        __builtin_amdgcn_s_setprio(1);
#pragma unroll
        for (int ii = 0; ii < 4; ii++)
#pragma unroll
            for (int j = 0; j < 3; j++)
                acc[ii][j] = MFMA16(af[ii], bfr[j], acc[ii][j]);
        __builtin_amdgcn_s_setprio(0);
        BAR();

        // ---------- phase 4: (ks1, m-half1) ----------
        if (pf && bwave) stageB(nxt, kt + 1, 1);
#pragma unroll
        for (int ii = 0; ii < 4; ii++) {
            const int row = wm + 64 + ii * 16 + lo;
            af[ii] = *(const bf16x8*)(A1 + row * 32 + ((qd ^ ((row >> 1) & 3)) << 3));
        }
        LGKM0();
        __builtin_amdgcn_s_setprio(1);
#pragma unroll
        for (int ii = 0; ii < 4; ii++)
#pragma unroll
            for (int j = 0; j < 3; j++)
                acc[4 + ii][j] = MFMA16(af[ii], bfr[j], acc[4 + ii][j]);
        __builtin_amdgcn_s_setprio(0);
        BAR();
    }

    // ---- unified epilogue: Q/K scatter + V transpose (handles straddle) ----
    const bool hasV = (n0 + BN > 2 * D_);
    __bf16* vt = (__bf16*)smem;            // [BN][RP]
    __syncthreads();
#pragma unroll
    for (int i = 0; i < 8; i++) {
#pragma unroll
        for (int j = 0; j < 3; j++) {
#pragma unroll
            for (int r = 0; r < 4; r++) {
                const int lrow = wn + j * 16 + lo;        // gn-local
                const int gn   = n0 + lrow;
                const int gm   = m0 + wm + i * 16 + qd * 4 + r;
                float v = acc[i][j][r] + bias[gn];
                if (gn >= 2 * D_) {                       // V: LDS transpose
                    const int lcol = wm + i * 16 + qd * 4 + r;
                    vt[lrow * RP + lcol] = (__bf16)v;
                } else {                                  // Q/K scatter
                    int which = gn >> 10;                 // 0=q 1=k
                    int bh = ((gm >> 11) << 4) + ((gn >> 6) & 15);
                    int dd = gn & 63;
                    int t  = gm & (T_ - 1);
                    if (which == 0)
                        Q[((size_t)bh * T_ + t) * DH_ + dd] = (__bf16)(v * QSCALE);
                    else
                        Kb[((size_t)bh * T_ + t) * DH_ + dd] = (__bf16)v;
                }
            }
        }
    }
    if (hasV) {
        __syncthreads();
        const int row = tid >> 1;          // gn-local row
        const int seg = tid & 1;           // 2 threads/row, 128 elems each
        if (row < BN && n0 + row >= 2 * D_) {
            const int gn  = n0 + row;
            const int bhv = ((m0 >> 11) << 4) + ((gn >> 6) & 15);
            const int dd  = gn & 63;
            __bf16* dst = Vt + ((size_t)bhv * DH_ + dd) * T_ + (m0 & (T_ - 1)) + seg * 128;
            const __bf16* src = vt + row * RP + seg * 128;
#pragma unroll
            for (int kk = 0; kk < 16; kk++)    // 16B stores
                *(uint4*)(dst + kk * 8) = *(const uint4*)(src + kk * 8);
        }
    }
}

// ------------------------------- MFMA GEMM ---------------------------------
// (proj only)  C[M][N] = A[M][K] @ Bt[N][K]^T + bias.  Now 128x128 tiles
// (R0's proven config): grid 8x32 = 256 blocks = 1/CU.  3-deep LDS pipeline,
// vmcnt(loads-per-tile) waits, raw s_barrier, XOR-swizzled staging.

template <int EPI, int TM, int TN>
__global__ __launch_bounds__(256) void gemm_bt_kernel(
    const __bf16* __restrict__ A, const __bf16* __restrict__ Bt,
    const float* __restrict__ bias, float* __restrict__ Cout,
    __bf16* __restrict__ Q, __bf16* __restrict__ Kb, __bf16* __restrict__ Vt,
    int M, int N, int K) {
    constexpr int MI  = TM / 32;          // m-frags per wave
    constexpr int NJ  = TN / 32;          // n-frags per wave
    constexpr int WM  = MI * 16;          // rows per wave
    constexpr int WN  = NJ * 16;          // cols per wave
    constexpr int ACH = TM / 64;          // A-chunk rounds per thread
    constexpr int BCH = TN / 64;          // B-chunk rounds per thread
    constexpr int RP  = TM + 8;           // vt tile row stride (elems)
    constexpr int SMEM_STAGE = 3 * (TM + TN) * 32 * 2;
    constexpr int SMEM_VT    = (EPI == 0) ? TN * RP * 2 : 0;
    constexpr int SMEM_BYTES = SMEM_STAGE > SMEM_VT ? SMEM_STAGE : SMEM_VT;
    __shared__ __align__(16) char smem[SMEM_BYTES];
    __bf16* AsB = (__bf16*)smem;          // [3][TM*32]
    __bf16* BsB = AsB + 3 * TM * 32;      // [3][TN*32]

    const int tid  = threadIdx.x;
    const int lane = tid & 63;
    const int wave = tid >> 6;
    const int lo   = lane & 15;
    const int qd   = lane >> 4;
    const int wm   = (wave >> 1) * WM;
    const int wn   = (wave & 1) * WN;
    const int m0   = blockIdx.y * TM;
    const int n0   = blockIdx.x * TN;

    const __bf16* gA[ACH];
    const __bf16* gB[BCH];
#pragma unroll
    for (int c = 0; c < ACH; c++) {
        int g = tid + 256 * c;
        int cc = (g & 3) ^ ((g >> 3) & 3);
        gA[c] = A + (size_t)(m0 + (g >> 2)) * K + cc * 8;
    }
#pragma unroll
    for (int c = 0; c < BCH; c++) {
        int g = tid + 256 * c;
        int cc = (g & 3) ^ ((g >> 3) & 3);
        gB[c] = Bt + (size_t)(n0 + (g >> 2)) * K + cc * 8;
    }

    f32x4 acc[MI][NJ] = {};
    const int nk = K >> 5;

    // prologue: stage tiles 0 and 1 (2-deep)
#pragma unroll
    for (int pb = 0; pb < 2; pb++) {
        const int k0 = pb << 5;
#pragma unroll
        for (int c = 0; c < ACH; c++)
            GLOAD16(gA[c] + k0, AsB + pb * TM * 32 + (tid + 256 * c) * 8);
#pragma unroll
        for (int c = 0; c < BCH; c++)
            GLOAD16(gB[c] + k0, BsB + pb * TN * 32 + (tid + 256 * c) * 8);
    }

    for (int kt = 0; kt < nk; kt++) {
        const int cur = kt % 3;
        if (kt + 1 < nk) {
            __asm__ volatile("s_waitcnt vmcnt(%0) lgkmcnt(0)" ::
                             "i"(ACH + BCH) : "memory");
        } else {
            __asm__ volatile("s_waitcnt vmcnt(0) lgkmcnt(0)" ::: "memory");
        }
        __asm__ volatile("s_barrier" ::: "memory");
        if (kt + 2 < nk) {
            const int k0n = (kt + 2) << 5;
            const int nb  = (kt + 2) % 3;
#pragma unroll
            for (int c = 0; c < ACH; c++)
                GLOAD16(gA[c] + k0n, AsB + nb * TM * 32 + (tid + 256 * c) * 8);
#pragma unroll
            for (int c = 0; c < BCH; c++)
                GLOAD16(gB[c] + k0n, BsB + nb * TN * 32 + (tid + 256 * c) * 8);
        }
        bf16x8 af[MI], bfr[NJ];
#pragma unroll
        for (int i = 0; i < MI; i++) {
            const int row = wm + i * 16 + lo;
            af[i] = *(const bf16x8*)(AsB + cur * TM * 32 + row * 32 +
                                     ((qd ^ ((row >> 1) & 3)) << 3));
        }
#pragma unroll
        for (int j = 0; j < NJ; j++) {
            const int row = wn + j * 16 + lo;
            bfr[j] = *(const bf16x8*)(BsB + cur * TN * 32 + row * 32 +
                                      ((qd ^ ((row >> 1) & 3)) << 3));
        }
#pragma unroll
        for (int i = 0; i < MI; i++)
#pragma unroll
            for (int j = 0; j < NJ; j++)
                acc[i][j] = MFMA16(af[i], bfr[j], acc[i][j]);
    }

    if (EPI == 0 && n0 >= 2 * D_) {
        __bf16* vt = (__bf16*)smem;
        __syncthreads();
#pragma unroll
        for (int i = 0; i < MI; i++)
#pragma unroll
            for (int j = 0; j < NJ; j++)
#pragma unroll
                for (int r = 0; r < 4; r++) {
                    const int lrow = wn + j * 16 + lo;
                    const int lcol = wm + i * 16 + qd * 4 + r;
                    vt[lrow * RP + lcol] =
                        (__bf16)(acc[i][j][r] + bias[n0 + lrow]);
                }
        __syncthreads();
        constexpr int TPR = 256 / TN;
        constexpr int SEG = TM / TPR;
        const int row = tid / TPR;
        const int seg = tid % TPR;
        const int gn  = n0 + row;
        const int bhv = ((m0 >> 11) << 4) + ((gn >> 6) & 15);
        const int dd  = gn & 63;
        __bf16* dst = Vt + ((size_t)bhv * DH_ + dd) * T_ + (m0 & (T_ - 1)) + seg * SEG;
        const __bf16* src = vt + row * RP + seg * SEG;
#pragma unroll
        for (int kk = 0; kk < SEG / 8; kk++)
            *(uint4*)(dst + kk * 8) = *(const uint4*)(src + kk * 8);
        return;
    }

#pragma unroll
    for (int i = 0; i < MI; i++) {
#pragma unroll
        for (int j = 0; j < NJ; j++) {
#pragma unroll
            for (int r = 0; r < 4; r++) {
                int gm = m0 + wm + i * 16 + qd * 4 + r;
                int gn = n0 + wn + j * 16 + lo;
                float v = acc[i][j][r] + bias[gn];
                if (EPI == 1) {
                    Cout[(size_t)gm * N + gn] = v;
                } else {
                    int which = gn >> 10;
                    int bh = ((gm >> 11) << 4) + ((gn >> 6) & 15);
                    int dd = gn & 63;
                    int t  = gm & (T_ - 1);
                    if (which == 0)
                        Q[((size_t)bh * T_ + t) * DH_ + dd] = (__bf16)(v * QSCALE);
                    else
                        Kb[((size_t)bh * T_ + t) * DH_ + dd] = (__bf16)v;
                }
            }
        }
    }
}

// ---------------------------- flash attention ------------------------------
// R24 kernel.  Grid 1024 (4 blocks/CU, 32KB LDS), balanced quadruple item
// map, heads XCD-pinned, K/V dbuf + prefetch, XOR-swizzled staging, fixed
// m=0 softmax, in-register softmax (swapped QK^T + cvt_pk + permlane).
// NEW: key-split waves.  wave w = (qh=w>>1, kh=w&1): partial O(32q x 64d)
// over the 32-key half kh of every tile.  Halves K/V ds_reads per wave at
// constant MFMA count; partials combined once at the end via LDS.

__global__ __launch_bounds__(256, 4) void attn_kernel(
    const __bf16* __restrict__ Q,   // [BH][T][64], pre-scaled
    const __bf16* __restrict__ Kb,  // [BH][T][64]
    const __bf16* __restrict__ Vt,  // [BH][64][T]
    __bf16* __restrict__ O) {       // [B][T][H*64]
    // single 32KB block: Ks dbuf = [0,16KB), Vs dbuf = [16KB,32KB);
    // reused as fp32 combine scratch after the main loop.
    __shared__ __align__(16) __bf16 KV[4 * 4096];

    const int tid  = threadIdx.x;
    const int wave = tid >> 6;
    const int lane = tid & 63;
    const int lo   = lane & 15;
    const int qd   = lane >> 4;
    const int qh   = wave >> 1;           // q-half (0: rows 0-31, 1: 32-63)
    const int kh   = wave & 1;            // key-half (0: keys 0-31, 1: 32-63)

    // staging decode: chunk g -> LDS byte g*16; row=g>>3, cc_lds=g&7,
    // global cc = cc_lds ^ (row&7)
    const int g0  = wave * 128 + lane;
    const int g1  = g0 + 64;
    const int r0s = g0 >> 3, c0s = (g0 & 7) ^ (r0s & 7);
    const int r1s = g1 >> 3, c1s = (g1 & 7) ^ (r1s & 7);
    const int so0 = wave * 1024;
    const int so1 = wave * 1024 + 512;

    bf16x8 ones;
#pragma unroll
    for (int i = 0; i < 8; i++) ones[i] = (__bf16)1.0f;

    // balanced item map: 4 blocks a CU receives cost exactly 66 tiles
    const int k  = blockIdx.x;            // 0..1023
    const int j  = k >> 5;                // 0..31
    const int bh = k & 31;
    int x;
    if (j < 8)       x = 31 - j;
    else if (j < 16) x = j - 8;
    else if (j < 24) x = 39 - j;
    else             x = j - 16;

    const int b     = bh >> 4;
    const int h     = bh & 15;
    const int q0    = x * 64;             // block q-origin (64 rows)
    const int qbase = q0 + qh * 32;       // wave q-origin (32 rows)

    const __bf16* Qh = Q + (size_t)bh * T_ * DH_;
    const __bf16* Kh = Kb + (size_t)bh * T_ * DH_;
    const __bf16* Vh = Vt + (size_t)bh * DH_ * T_;

    // Q frags: qa[qt][half]: lane holds Q[qbase+qt*16+lo][half*32+qd*8 ..]
    bf16x8 qa[2][2];
#pragma unroll
    for (int qt = 0; qt < 2; qt++)
#pragma unroll
        for (int hf = 0; hf < 2; hf++)
            qa[qt][hf] = *(const bf16x8*)(Qh + (size_t)(qbase + qt * 16 + lo) * DH_ +
                                          hf * 32 + qd * 8);

    f32x4 oacc[2][4] = {};                // [qt][d-group] partial O
    float lrow[2][4] = {};                // [qt][r] partial row sums
    const int ntile = x + 1;

    // prologue: stage tile 0 into buffer 0
    GLOAD16(Kh + (size_t)r0s * DH_ + c0s * 8, KV + so0);
    GLOAD16(Kh + (size_t)r1s * DH_ + c1s * 8, KV + so1);
    GLOAD16(Vh + (size_t)r0s * T_ + c0s * 8, KV + 8192 + so0);
    GLOAD16(Vh + (size_t)r1s * T_ + c1s * 8, KV + 8192 + so1);
    DRAIN_ALL();
    __syncthreads();

    for (int t = 0; t < ntile; t++) {
        const int j0  = t << 6;
        const int cur = t & 1;
        const __bf16* Ksc = KV + cur * 4096;
        const __bf16* Vsc = KV + 8192 + cur * 4096;
        if (t + 1 < ntile) {             // prefetch next K/V tile
            const int j0n = j0 + 64;
            __bf16* Ksn = KV + (1 - cur) * 4096;
            __bf16* Vsn = KV + 8192 + (1 - cur) * 4096;
            GLOAD16(Kh + (size_t)(j0n + r0s) * DH_ + c0s * 8, Ksn + so0);
            GLOAD16(Kh + (size_t)(j0n + r1s) * DH_ + c1s * 8, Ksn + so1);
            GLOAD16(Vh + (size_t)r0s * T_ + j0n + c0s * 8, Vsn + so0);
            GLOAD16(Vh + (size_t)r1s * T_ + j0n + c1s * 8, Vsn + so1);
        }

        // ---- S^T over this wave's 32-key half: s[qt][g2] ----
        // C-layout: col(q-within-16)=lo, row(key-within-16)=qd*4+r
        f32x4 s[2][2] = {};
        __builtin_amdgcn_s_setprio(1);
#pragma unroll
        for (int g2 = 0; g2 < 2; g2++) {
            const int row = kh * 32 + g2 * 16 + lo;
            const __bf16* kr = Ksc + row * 64;
            bf16x8 kb0 = *(const bf16x8*)(kr + ((qd ^ (row & 7)) << 3));
            bf16x8 kb1 = *(const bf16x8*)(kr + (((4 + qd) ^ (row & 7)) << 3));
            s[0][g2] = MFMA16(kb0, qa[0][0], s[0][g2]);
            s[0][g2] = MFMA16(kb1, qa[0][1], s[0][g2]);
            s[1][g2] = MFMA16(kb0, qa[1][0], s[1][g2]);
            s[1][g2] = MFMA16(kb1, qa[1][1], s[1][g2]);
        }
        __builtin_amdgcn_s_setprio(0);

        // ---- causal mask (wave-uniform gate on this key-half) ----
        if (j0 + kh * 32 + 31 > qbase) {
#pragma unroll
            for (int qt = 0; qt < 2; qt++) {
                const int qg = qbase + qt * 16 + lo;
#pragma unroll
                for (int g2 = 0; g2 < 2; g2++) {
                    const int kbase = j0 + kh * 32 + g2 * 16 + qd * 4;
#pragma unroll
                    for (int r = 0; r < 4; r++)
                        s[qt][g2][r] = (kbase + r <= qg) ? s[qt][g2][r] : -1e30f;
                }
            }
        }

        // ---- P = exp2(S) packed to bf16 A-frags in-register (per qt) ----
        bf16x8 pa[2];
#pragma unroll
        for (int qt = 0; qt < 2; qt++) {
            unsigned Aw[2], Bw[2];
#pragma unroll
            for (int g2 = 0; g2 < 2; g2++) {
                float p0 = __builtin_amdgcn_exp2f(s[qt][g2][0]);
                float p1 = __builtin_amdgcn_exp2f(s[qt][g2][1]);
                float p2 = __builtin_amdgcn_exp2f(s[qt][g2][2]);
                float p3 = __builtin_amdgcn_exp2f(s[qt][g2][3]);
                __asm__("v_cvt_pk_bf16_f32 %0, %1, %2" : "=v"(Aw[g2]) : "v"(p0), "v"(p1));
                __asm__("v_cvt_pk_bf16_f32 %0, %1, %2" : "=v"(Bw[g2]) : "v"(p2), "v"(p3));
            }
            xpose_pair(Aw[0], Aw[1]);
            xpose_pair(Bw[0], Bw[1]);
            u32x4 P = {Aw[0], Bw[0], Aw[1], Bw[1]};   // this wave's 32 keys
            pa[qt] = __builtin_bit_cast(bf16x8, P);
        }

        // ---- partial row sums (ones-trick) + partial O += P @ V ----
        f32x4 ps0 = {}, ps1 = {};
        __builtin_amdgcn_s_setprio(1);
        ps0 = MFMA16(pa[0], ones, ps0);
        ps1 = MFMA16(pa[1], ones, ps1);
#pragma unroll
        for (int c = 0; c < 4; c++) {
            const int row = c * 16 + lo;              // d
            const __bf16* vr = Vsc + row * 64;
            bf16x8 vb = *(const bf16x8*)(vr + (((kh * 4 + qd) ^ (row & 7)) << 3));
            oacc[0][c] = MFMA16(pa[0], vb, oacc[0][c]);
            oacc[1][c] = MFMA16(pa[1], vb, oacc[1][c]);
        }
        __builtin_amdgcn_s_setprio(0);
#pragma unroll
        for (int r = 0; r < 4; r++) { lrow[0][r] += ps0[r]; lrow[1][r] += ps1[r]; }

        DRAIN_ALL();                 // prefetch landed + all LDS ops done
        __syncthreads();
    }

    // ---- combine kh partials (LDS now free), normalize, store ----
    // scratch: per qh: oacc [32 q][64 d] at stride 65 (pad kills conflicts)
    // + lrow[32] at +2080.  2 x 2144 floats = 17KB <= 32KB.
    float* cb = (float*)KV;
    const int qoff = qh * 2144;
    if (kh == 1) {
#pragma unroll
        for (int qt = 0; qt < 2; qt++) {
#pragma unroll
            for (int c = 0; c < 4; c++)
#pragma unroll
                for (int r = 0; r < 4; r++)
                    cb[qoff + (qt * 16 + qd * 4 + r) * 65 + c * 16 + lo] =
                        oacc[qt][c][r];
#pragma unroll
            for (int r = 0; r < 4; r++)    // 16 lanes write same value: benign
                cb[qoff + 2080 + qt * 16 + qd * 4 + r] = lrow[qt][r];
        }
    }
    __syncthreads();
    if (kh == 0) {
#pragma unroll
        for (int qt = 0; qt < 2; qt++) {
#pragma unroll
            for (int r = 0; r < 4; r++)
                lrow[qt][r] += cb[qoff + 2080 + qt * 16 + qd * 4 + r];
            float inv[4];
#pragma unroll
            for (int r = 0; r < 4; r++) inv[r] = 1.0f / lrow[qt][r];
#pragma unroll
            for (int c = 0; c < 4; c++) {
#pragma unroll
                for (int r = 0; r < 4; r++) {
                    float val = oacc[qt][c][r] +
                                cb[qoff + (qt * 16 + qd * 4 + r) * 65 + c * 16 + lo];
                    val *= inv[r];
                    size_t idx = ((size_t)b * T_ + (qbase + qt * 16 + qd * 4 + r)) * D_ +
                                 h * DH_ + c * 16 + lo;
                    O[idx] = (__bf16)val;
                }
            }
        }
    }
}

// -------------------------------- launcher ---------------------------------

extern "C" void kernel_launch(void* const* d_in, const int* in_sizes, int n_in,
                              void* d_out, int out_size, void* d_ws, size_t ws_size,
                              hipStream_t stream) {
    const float* x      = (const float*)d_in[0];
    const float* w_attn = (const float*)d_in[1];
    const float* b_attn = (const float*)d_in[2];
    const float* w_proj = (const float*)d_in[3];
    const float* b_proj = (const float*)d_in[4];
    float* out = (float*)d_out;

    const size_t MB = (size_t)1 << 20;
    if (ws_size < 48 * MB) return;   // need 48 MB scratch

    char* ws = (char*)d_ws;
    __bf16* xb     = (__bf16*)(ws);              //  8 MB  [M][D]
    __bf16* wattnT = (__bf16*)(ws + 8 * MB);     //  6 MB  [3D][D]
    __bf16* wprojT = (__bf16*)(ws + 14 * MB);    //  2 MB  [D][D]
    __bf16* Qb     = (__bf16*)(ws + 16 * MB);    //  8 MB  [BH][T][64]
    __bf16* Kb     = (__bf16*)(ws + 24 * MB);    //  8 MB  [BH][T][64]
    __bf16* Vt     = (__bf16*)(ws + 32 * MB);    //  8 MB  [BH][64][T]
    __bf16* Ob     = (__bf16*)(ws + 40 * MB);    //  8 MB  [M][D]

    // 1. fused prep: x convert + both weight transposes
    prep_kernel<<<dim3(8192), 256, 0, stream>>>(x, xb, w_attn, wattnT,
                                                w_proj, wprojT);
    // 2. QKV GEMM -> Q(scaled)/K/Vt  (256x192 tiles, 256 blocks = 1/CU)
    qkv_gemm256_kernel<<<dim3(16, 16), 512, 0, stream>>>(
        xb, wattnT, b_attn, Qb, Kb, Vt);
    // 3. causal flash attention (1024 blocks, 4/CU, key-split waves)
    attn_kernel<<<dim3(1024), 256, 0, stream>>>(Qb, Kb, Vt, Ob);
    // 4. output projection (fp32 + bias), 128x128 tiles -> 256 blocks = 1/CU
    gemm_bt_kernel<1, 128, 128><<<dim3(D_ / 128, M_ / 128), 256, 0, stream>>>(
        Ob, wprojT, b_proj, out, nullptr, nullptr, nullptr, M_, D_, D_);
}